// Round 1
// baseline (2240.879 us; speedup 1.0000x reference)
//
#include <hip/hip_runtime.h>
#include <math.h>

#define NN  8
#define CIN 128
#define HH  36
#define WW  36
#define HW  1296
#define CC  256
#define GG  8
#define HC  32
#define DDH 34
#define DDS 1156  /* 34*34 */

__device__ __forceinline__ float sigmoidf_(float x) {
    return 1.f / (1.f + __expf(-x));
}
__device__ __forceinline__ float tanhf_(float x) {
    float xa = fminf(fmaxf(x, -15.f), 15.f);
    float e = __expf(2.f * xa);
    return (e - 1.f) / (e + 1.f);
}

// ---------------- kernel 1: xx = 1x1 conv(x, Wx), no bias ----------------
__global__ void k_xx(const float* __restrict__ x, const float* __restrict__ Wx,
                     float* __restrict__ xx) {
    int b  = blockIdx.x;
    int n  = b >> 8, co = b & 255;
    const float* wrow = Wx + co * CIN;
    const float4* xin = (const float4*)(x + n * CIN * HW);
    float4* out = (float4*)(xx + (n * CC + co) * HW);
    for (int wi = threadIdx.x; wi < HW / 4; wi += blockDim.x) {
        float4 s = {0.f, 0.f, 0.f, 0.f};
        #pragma unroll 8
        for (int ci = 0; ci < CIN; ++ci) {
            float w = wrow[ci];
            float4 xv = xin[ci * (HW / 4) + wi];
            s.x = fmaf(w, xv.x, s.x);
            s.y = fmaf(w, xv.y, s.y);
            s.z = fmaf(w, xv.z, s.z);
            s.w = fmaf(w, xv.w, s.w);
        }
        out[wi] = s;
    }
}

// ---------------- kernel 2: q (SAME), k,v (VALID) grouped 3x3 convs ----------------
__global__ void k_qkv(const float* __restrict__ xx, const float* __restrict__ h0,
                      const float* __restrict__ Wq, const float* __restrict__ Wk,
                      const float* __restrict__ Wv,
                      float* __restrict__ q, float* __restrict__ k, float* __restrict__ v) {
    int b  = blockIdx.x;
    int n  = b >> 8, co = b & 255;
    int g  = co >> 5;
    __shared__ float wq_l[576], wk_l[576], wv_l[576];
    for (int e = threadIdx.x; e < 576; e += blockDim.x) {
        wq_l[e] = Wq[co * 576 + e];
        wk_l[e] = Wk[co * 576 + e];
        wv_l[e] = Wv[co * 576 + e];
    }
    __syncthreads();
    float* qout = q + (n * CC + co) * HW;
    float* kout = k + (n * CC + co) * DDS;
    float* vout = v + (n * CC + co) * DDS;
    for (int wi = threadIdx.x; wi < 324; wi += blockDim.x) {
        int y = wi / 9, xc = (wi % 9) * 4;
        float qa[4] = {0,0,0,0}, ka[4] = {0,0,0,0}, va[4] = {0,0,0,0};
        for (int ic = 0; ic < 64; ++ic) {
            const float* src = (ic < HC)
                ? (xx + (size_t)(n * CC + g * HC + ic) * HW)
                : (h0 + (size_t)(n * CC + g * HC + (ic - HC)) * HW);
            float win[4][8];
            #pragma unroll
            for (int r = 0; r < 4; ++r) {
                int row = y - 1 + r;
                bool rv = (row >= 0 && row < HH);
                #pragma unroll
                for (int cix = 0; cix < 8; ++cix) {
                    int col = xc - 1 + cix;
                    win[r][cix] = (rv && col >= 0 && col < WW) ? src[row * WW + col] : 0.f;
                }
            }
            const float* wq_ = &wq_l[ic * 9];
            const float* wk_ = &wk_l[ic * 9];
            const float* wv_ = &wv_l[ic * 9];
            #pragma unroll
            for (int ky = 0; ky < 3; ++ky) {
                #pragma unroll
                for (int kx = 0; kx < 3; ++kx) {
                    float wqv = wq_[ky * 3 + kx];
                    float wkv = wk_[ky * 3 + kx];
                    float wvv = wv_[ky * 3 + kx];
                    #pragma unroll
                    for (int dx = 0; dx < 4; ++dx) {
                        qa[dx] = fmaf(wqv, win[ky][dx + kx], qa[dx]);
                        ka[dx] = fmaf(wkv, win[ky + 1][dx + kx + 1], ka[dx]);
                        va[dx] = fmaf(wvv, win[ky + 1][dx + kx + 1], va[dx]);
                    }
                }
            }
        }
        #pragma unroll
        for (int dx = 0; dx < 4; ++dx) {
            qout[y * WW + xc + dx] = qa[dx];
            int xk = xc + dx;
            if (y < DDH && xk < DDH) {
                kout[y * DDH + xk] = ka[dx];
                vout[y * DDH + xk] = va[dx];
            }
        }
    }
}

// ---------------- kernel 3: attention, one thread = one q row ----------------
__global__ void k_attn(const float* __restrict__ q, const float* __restrict__ k,
                       const float* __restrict__ v, const float* __restrict__ tau,
                       float* __restrict__ a) {
    int b   = blockIdx.x;
    int ng  = b / 6;
    int qb  = (b % 6) * 256;
    int g   = ng & 7;
    __shared__ float KT[32][64];
    __shared__ float VT[32][64];
    int row   = qb + threadIdx.x;
    bool valid = row < HW;
    int r = valid ? row : 0;
    const float* qbase = q + (size_t)ng * 32 * HW;
    const float* kbase = k + (size_t)ng * 32 * DDS;
    const float* vbase = v + (size_t)ng * 32 * DDS;
    float tg = tau[g];
    float qreg[32];
    #pragma unroll
    for (int c = 0; c < 32; ++c) qreg[c] = qbase[c * HW + r] * tg;
    float m = -1e30f, l = 0.f;
    float acc[32];
    #pragma unroll
    for (int c = 0; c < 32; ++c) acc[c] = 0.f;

    for (int dt = 0; dt < DDS; dt += 64) {
        int dcount = min(64, DDS - dt);
        __syncthreads();
        for (int e = threadIdx.x; e < 2048; e += 256) {
            int c = e >> 6, d = e & 63;
            float kv = 0.f, vv = 0.f;
            if (d < dcount) {
                kv = kbase[c * DDS + dt + d];
                vv = vbase[c * DDS + dt + d];
            }
            KT[c][d] = kv;
            VT[c][d] = vv;
        }
        __syncthreads();
        for (int j0 = 0; j0 < dcount; j0 += 16) {
            int jc = min(16, dcount - j0);
            float lg[16];
            #pragma unroll
            for (int j = 0; j < 16; ++j) lg[j] = 0.f;
            #pragma unroll
            for (int c = 0; c < 32; ++c) {
                float qc = qreg[c];
                const float4* kp = (const float4*)&KT[c][j0];
                #pragma unroll
                for (int j4 = 0; j4 < 4; ++j4) {
                    float4 kv = kp[j4];
                    lg[j4 * 4 + 0] = fmaf(qc, kv.x, lg[j4 * 4 + 0]);
                    lg[j4 * 4 + 1] = fmaf(qc, kv.y, lg[j4 * 4 + 1]);
                    lg[j4 * 4 + 2] = fmaf(qc, kv.z, lg[j4 * 4 + 2]);
                    lg[j4 * 4 + 3] = fmaf(qc, kv.w, lg[j4 * 4 + 3]);
                }
            }
            float mc = -1e30f;
            for (int j = 0; j < jc; ++j) mc = fmaxf(mc, lg[j]);
            if (mc > m) {
                float sc = __expf(m - mc);
                l *= sc;
                #pragma unroll
                for (int c = 0; c < 32; ++c) acc[c] *= sc;
                m = mc;
            }
            float p[16];
            float ls = 0.f;
            for (int j = 0; j < 16; ++j) {
                float pv = (j < jc) ? __expf(lg[j] - m) : 0.f;
                p[j] = pv;
                ls += pv;
            }
            l += ls;
            #pragma unroll
            for (int c = 0; c < 32; ++c) {
                const float4* vp = (const float4*)&VT[c][j0];
                float s = acc[c];
                #pragma unroll
                for (int j4 = 0; j4 < 4; ++j4) {
                    float4 vv = vp[j4];
                    s = fmaf(p[j4 * 4 + 0], vv.x, s);
                    s = fmaf(p[j4 * 4 + 1], vv.y, s);
                    s = fmaf(p[j4 * 4 + 2], vv.z, s);
                    s = fmaf(p[j4 * 4 + 3], vv.w, s);
                }
                acc[c] = s;
            }
        }
    }
    if (valid) {
        float inv = 1.f / l;
        float* abase = a + (size_t)ng * 32 * HW;
        #pragma unroll
        for (int c = 0; c < 32; ++c) abase[c * HW + row] = acc[c] * inv;
    }
}

// ---------------- kernel 4: gates + LSTM combine ----------------
__global__ void k_gates(const float* __restrict__ xx, const float* __restrict__ h0,
                        const float* __restrict__ c0, const float* __restrict__ a,
                        const float* __restrict__ Wi1, const float* __restrict__ Wi2, const float* __restrict__ bi,
                        const float* __restrict__ Wf1, const float* __restrict__ Wf2, const float* __restrict__ bf,
                        const float* __restrict__ Wg1, const float* __restrict__ Wg2, const float* __restrict__ bg,
                        const float* __restrict__ Wo1, const float* __restrict__ Wo2, const float* __restrict__ bo,
                        float* __restrict__ out) {
    int b  = blockIdx.x;
    int n  = b >> 8, co = b & 255;
    int g  = co >> 5;
    __shared__ float w2[4][576];
    __shared__ float w1[4][32];
    __shared__ float bb[4];
    for (int e = threadIdx.x; e < 576; e += blockDim.x) {
        w2[0][e] = Wi2[co * 576 + e];
        w2[1][e] = Wf2[co * 576 + e];
        w2[2][e] = Wg2[co * 576 + e];
        w2[3][e] = Wo2[co * 576 + e];
    }
    if (threadIdx.x < 32) {
        int e = threadIdx.x;
        w1[0][e] = Wi1[co * 32 + e];
        w1[1][e] = Wf1[co * 32 + e];
        w1[2][e] = Wg1[co * 32 + e];
        w1[3][e] = Wo1[co * 32 + e];
    }
    if (threadIdx.x == 0) {
        bb[0] = bi[co]; bb[1] = bf[co]; bb[2] = bg[co]; bb[3] = bo[co];
    }
    __syncthreads();
    for (int wi = threadIdx.x; wi < 324; wi += blockDim.x) {
        int y = wi / 9, xc = (wi % 9) * 4;
        float acc[4][4];
        #pragma unroll
        for (int gt = 0; gt < 4; ++gt)
            #pragma unroll
            for (int dx = 0; dx < 4; ++dx) acc[gt][dx] = bb[gt];
        // 1x1 grouped conv on a
        const float* abase = a + (size_t)(n * CC + g * HC) * HW + y * WW + xc;
        #pragma unroll 8
        for (int j = 0; j < 32; ++j) {
            float4 av = *(const float4*)(abase + (size_t)j * HW);
            #pragma unroll
            for (int gt = 0; gt < 4; ++gt) {
                float wv = w1[gt][j];
                acc[gt][0] = fmaf(wv, av.x, acc[gt][0]);
                acc[gt][1] = fmaf(wv, av.y, acc[gt][1]);
                acc[gt][2] = fmaf(wv, av.z, acc[gt][2]);
                acc[gt][3] = fmaf(wv, av.w, acc[gt][3]);
            }
        }
        // 3x3 grouped SAME conv on xh
        for (int ic = 0; ic < 64; ++ic) {
            const float* src = (ic < HC)
                ? (xx + (size_t)(n * CC + g * HC + ic) * HW)
                : (h0 + (size_t)(n * CC + g * HC + (ic - HC)) * HW);
            float win[3][8];
            #pragma unroll
            for (int rr = 0; rr < 3; ++rr) {
                int rowi = y - 1 + rr;
                bool rv = (rowi >= 0 && rowi < HH);
                #pragma unroll
                for (int cix = 0; cix < 8; ++cix) {
                    int col = xc - 1 + cix;
                    win[rr][cix] = (rv && col >= 0 && col < WW) ? src[rowi * WW + col] : 0.f;
                }
            }
            #pragma unroll
            for (int ky = 0; ky < 3; ++ky) {
                #pragma unroll
                for (int kx = 0; kx < 3; ++kx) {
                    #pragma unroll
                    for (int gt = 0; gt < 4; ++gt) {
                        float wv = w2[gt][ic * 9 + ky * 3 + kx];
                        #pragma unroll
                        for (int dx = 0; dx < 4; ++dx)
                            acc[gt][dx] = fmaf(wv, win[ky][dx + kx], acc[gt][dx]);
                    }
                }
            }
        }
        const float* c0p = c0 + (size_t)(n * CC + co) * HW + y * WW + xc;
        float* op = out + (size_t)(n * CC + co) * HW + y * WW + xc;
        #pragma unroll
        for (int dx = 0; dx < 4; ++dx) {
            float iv = sigmoidf_(acc[0][dx]);
            float fv = sigmoidf_(acc[1][dx]);
            float gv = tanhf_(acc[2][dx]);
            float ov = sigmoidf_(acc[3][dx]);
            float cv = fmaf(fv, c0p[dx], iv * gv);
            op[dx] = ov * tanhf_(cv);
        }
    }
}

extern "C" void kernel_launch(void* const* d_in, const int* in_sizes, int n_in,
                              void* d_out, int out_size, void* d_ws, size_t ws_size,
                              hipStream_t stream) {
    const float* x   = (const float*)d_in[0];
    const float* h0  = (const float*)d_in[1];
    const float* c0  = (const float*)d_in[2];
    const float* Wx  = (const float*)d_in[3];
    const float* Wq  = (const float*)d_in[4];
    const float* Wk  = (const float*)d_in[5];
    const float* Wv  = (const float*)d_in[6];
    const float* Wi1 = (const float*)d_in[7];
    const float* Wi2 = (const float*)d_in[8];
    const float* bi  = (const float*)d_in[9];
    const float* Wf1 = (const float*)d_in[10];
    const float* Wf2 = (const float*)d_in[11];
    const float* bf  = (const float*)d_in[12];
    const float* Wg1 = (const float*)d_in[13];
    const float* Wg2 = (const float*)d_in[14];
    const float* bg  = (const float*)d_in[15];
    const float* Wo1 = (const float*)d_in[16];
    const float* Wo2 = (const float*)d_in[17];
    const float* bo  = (const float*)d_in[18];
    const float* tau = (const float*)d_in[19];

    float* ws  = (float*)d_ws;
    float* xx  = ws;                       // N*C*HW  = 2654208
    float* q   = xx + 2654208;             // N*C*HW  = 2654208
    float* k   = q  + 2654208;             // N*C*DDS = 2367488
    float* v   = k  + 2367488;             // N*C*DDS = 2367488
    float* a   = v  + 2367488;             // N*C*HW  = 2654208
    float* out = (float*)d_out;

    hipLaunchKernelGGL(k_xx,   dim3(NN * CC),     dim3(256), 0, stream, x, Wx, xx);
    hipLaunchKernelGGL(k_qkv,  dim3(NN * CC),     dim3(128), 0, stream, xx, h0, Wq, Wk, Wv, q, k, v);
    hipLaunchKernelGGL(k_attn, dim3(NN * GG * 6), dim3(256), 0, stream, q, k, v, tau, a);
    hipLaunchKernelGGL(k_gates,dim3(NN * CC),     dim3(128), 0, stream, xx, h0, c0, a,
                       Wi1, Wi2, bi, Wf1, Wf2, bf, Wg1, Wg2, bg, Wo1, Wo2, bo, out);
}

// Round 2
// 927.712 us; speedup vs baseline: 2.4155x; 2.4155x over previous
//
#include <hip/hip_runtime.h>
#include <math.h>

#define NN  8
#define CIN 128
#define HW  1296
#define CC  256
#define DDS 1156

typedef __attribute__((ext_vector_type(8))) short bvec8;
typedef __attribute__((ext_vector_type(4))) float fvec4;

__device__ __forceinline__ float sigmoidf_(float x) {
    return 1.f / (1.f + __expf(-x));
}
__device__ __forceinline__ float tanhf_(float x) {
    float xa = fminf(fmaxf(x, -15.f), 15.f);
    float e = __expf(2.f * xa);
    return (e - 1.f) / (e + 1.f);
}
__device__ __forceinline__ unsigned short f2bf(float f) {
    unsigned int u = __float_as_uint(f);
    u = (u + 0x7FFFu + ((u >> 16) & 1u)) >> 16;
    return (unsigned short)u;
}

// ---------------- kernel 1: xx = 1x1 conv(x, Wx), no bias (fp32) ----------------
__global__ void k_xx(const float* __restrict__ x, const float* __restrict__ Wx,
                     float* __restrict__ xx) {
    int b  = blockIdx.x;
    int n  = b >> 8, co = b & 255;
    const float* wrow = Wx + co * CIN;
    const float4* xin = (const float4*)(x + n * CIN * HW);
    float4* out = (float4*)(xx + (n * CC + co) * HW);
    for (int wi = threadIdx.x; wi < HW / 4; wi += blockDim.x) {
        float4 s = {0.f, 0.f, 0.f, 0.f};
        #pragma unroll 8
        for (int ci = 0; ci < CIN; ++ci) {
            float w = wrow[ci];
            float4 xv = xin[ci * (HW / 4) + wi];
            s.x = fmaf(w, xv.x, s.x);
            s.y = fmaf(w, xv.y, s.y);
            s.z = fmaf(w, xv.z, s.z);
            s.w = fmaf(w, xv.w, s.w);
        }
        out[wi] = s;
    }
}

// ---------------- weight packing: QKV -> MFMA A-fragments ----------------
__global__ void k_pack_qkv(const float* __restrict__ Wq, const float* __restrict__ Wk,
                           const float* __restrict__ Wv, unsigned short* __restrict__ apq) {
    int t = blockIdx.x * 256 + threadIdx.x;
    if (t >= 55296) return;
    int lane = t & 63;
    int t2 = t >> 6;
    int mf = t2 % 6, t3 = t2 / 6;
    int s = t3 % 18, g = t3 / 18;
    int kyx = s >> 1, icb = s & 1;
    int ky = kyx / 3, kx = kyx % 3;
    int m = mf * 16 + (lane & 15);
    int conv = m >> 5, cl = m & 31, co = g * 32 + cl;
    int ic0 = icb * 32 + (lane >> 4) * 8;
    const float* W = (conv == 0) ? Wq : (conv == 1 ? Wk : Wv);
    union { unsigned short us[8]; bvec8 v; } pk;
    #pragma unroll
    for (int j = 0; j < 8; ++j)
        pk.us[j] = f2bf(W[((co * 64 + ic0 + j) * 3 + ky) * 3 + kx]);
    *(bvec8*)(apq + (size_t)t * 8) = pk.v;
}

__global__ void k_pack_gates(const float* __restrict__ Wi2, const float* __restrict__ Wf2,
                             const float* __restrict__ Wg2, const float* __restrict__ Wo2,
                             const float* __restrict__ Wi1, const float* __restrict__ Wf1,
                             const float* __restrict__ Wg1, const float* __restrict__ Wo1,
                             unsigned short* __restrict__ apg2, unsigned short* __restrict__ apg1) {
    int t = blockIdx.x * 256 + threadIdx.x;
    if (t < 73728) {
        int lane = t & 63;
        int t2 = t >> 6;
        int mf = t2 % 8, t3 = t2 / 8;
        int s = t3 % 18, g = t3 / 18;
        int kyx = s >> 1, icb = s & 1;
        int ky = kyx / 3, kx = kyx % 3;
        int m = mf * 16 + (lane & 15);
        int gate = m >> 5, cl = m & 31, co = g * 32 + cl;
        int ic0 = icb * 32 + (lane >> 4) * 8;
        const float* W = (gate == 0) ? Wi2 : (gate == 1 ? Wf2 : (gate == 2 ? Wg2 : Wo2));
        union { unsigned short us[8]; bvec8 v; } pk;
        #pragma unroll
        for (int j = 0; j < 8; ++j)
            pk.us[j] = f2bf(W[((co * 64 + ic0 + j) * 3 + ky) * 3 + kx]);
        *(bvec8*)(apg2 + (size_t)t * 8) = pk.v;
    } else if (t < 77824) {
        int u = t - 73728;
        int lane = u & 63;
        int t2 = u >> 6;
        int mf = t2 % 8, g = t2 / 8;
        int m = mf * 16 + (lane & 15);
        int gate = m >> 5, cl = m & 31, co = g * 32 + cl;
        int k0 = (lane >> 4) * 8;
        const float* W = (gate == 0) ? Wi1 : (gate == 1 ? Wf1 : (gate == 2 ? Wg1 : Wo1));
        union { unsigned short us[8]; bvec8 v; } pk;
        #pragma unroll
        for (int j = 0; j < 8; ++j)
            pk.us[j] = f2bf(W[co * 32 + k0 + j]);
        *(bvec8*)(apg1 + (size_t)u * 8) = pk.v;
    }
}

// ---------------- kernel 2: MFMA grouped 3x3 conv -> q (SAME), k,v (interior) ----------------
__global__ __launch_bounds__(384) void k_qkv_mfma(
        const float* __restrict__ xx, const float* __restrict__ h0,
        const unsigned short* __restrict__ apq,
        float* __restrict__ q, float* __restrict__ k, float* __restrict__ v) {
    int bid = blockIdx.x;
    int n = bid / 72, rem = bid % 72;
    int g = rem / 9, yt = rem % 9;
    __shared__ bvec8 sm[1824];
    int tid = threadIdx.x;
    for (int u = tid; u < 1824; u += 384) {
        int col = u % 38; int t2 = u / 38;
        int icb = t2 % 8; int rr = t2 / 8;
        int y = yt * 4 - 1 + rr, cx = col - 1;
        union { unsigned short us[8]; bvec8 v; } pk;
        if (y >= 0 && y < 36 && cx >= 0 && cx < 36) {
            const float* src = (icb < 4)
                ? (xx + (size_t)(n * CC + g * 32 + icb * 8) * HW)
                : (h0 + (size_t)(n * CC + g * 32 + (icb - 4) * 8) * HW);
            int off = y * 36 + cx;
            #pragma unroll
            for (int j = 0; j < 8; ++j) pk.us[j] = f2bf(src[(size_t)j * HW + off]);
        } else {
            #pragma unroll
            for (int j = 0; j < 8; ++j) pk.us[j] = 0;
        }
        int s = rr * 38 + col;
        sm[s * 8 + (icb ^ (s & 7))] = pk.v;
    }
    __syncthreads();
    int lane = tid & 63, w = tid >> 6;
    int mg = w % 3, nh = w / 3;
    int kgrp = lane >> 4;
    int nf0 = nh * 4;
    int sb[5], pl[5];
    #pragma unroll
    for (int jn = 0; jn < 5; ++jn) {
        int p = (nf0 + jn) * 16 + (lane & 15);
        pl[jn] = p;
        sb[jn] = (p / 36) * 38 + (p % 36);
    }
    fvec4 acc[2][5];
    #pragma unroll
    for (int i = 0; i < 2; ++i)
        #pragma unroll
        for (int jn = 0; jn < 5; ++jn)
            acc[i][jn] = fvec4{0.f, 0.f, 0.f, 0.f};
    const bvec8* ap = (const bvec8*)apq + (size_t)g * 6912 + mg * 128 + lane;
    for (int s = 0; s < 18; ++s) {
        int kyx = s >> 1, icb = s & 1;
        int ky = kyx / 3, kx = kyx % 3;
        bvec8 a0 = ap[0], a1 = ap[64];
        ap += 384;
        int soff = ky * 38 + kx;
        int ib = icb * 4 + kgrp;
        #pragma unroll
        for (int jn = 0; jn < 5; ++jn) {
            int slot = sb[jn] + soff;
            bvec8 bfr = sm[slot * 8 + (ib ^ (slot & 7))];
            acc[0][jn] = __builtin_amdgcn_mfma_f32_16x16x32_bf16(a0, bfr, acc[0][jn], 0, 0, 0);
            acc[1][jn] = __builtin_amdgcn_mfma_f32_16x16x32_bf16(a1, bfr, acc[1][jn], 0, 0, 0);
        }
    }
    #pragma unroll
    for (int i = 0; i < 2; ++i) {
        int mf = mg * 2 + i;
        #pragma unroll
        for (int jn = 0; jn < 5; ++jn) {
            int gp = yt * 144 + pl[jn];
            int py = gp / 36, px = gp % 36;
            #pragma unroll
            for (int r = 0; r < 4; ++r) {
                int m = mf * 16 + kgrp * 4 + r;
                int conv = m >> 5, c = m & 31;
                float val = acc[i][jn][r];
                if (conv == 0) {
                    q[(size_t)(n * CC + g * 32 + c) * HW + gp] = val;
                } else if (py >= 1 && py <= 34 && px >= 1 && px <= 34) {
                    float* dst = (conv == 1) ? k : v;
                    dst[(size_t)(n * CC + g * 32 + c) * DDS + (py - 1) * 34 + (px - 1)] = val;
                }
            }
        }
    }
}

// ---------------- kernel 3: attention (fp32, unchanged) ----------------
__global__ void k_attn(const float* __restrict__ q, const float* __restrict__ k,
                       const float* __restrict__ v, const float* __restrict__ tau,
                       float* __restrict__ a) {
    int b   = blockIdx.x;
    int ng  = b / 6;
    int qb  = (b % 6) * 256;
    int g   = ng & 7;
    __shared__ float KT[32][64];
    __shared__ float VT[32][64];
    int row   = qb + threadIdx.x;
    bool valid = row < HW;
    int r = valid ? row : 0;
    const float* qbase = q + (size_t)ng * 32 * HW;
    const float* kbase = k + (size_t)ng * 32 * DDS;
    const float* vbase = v + (size_t)ng * 32 * DDS;
    float tg = tau[g];
    float qreg[32];
    #pragma unroll
    for (int c = 0; c < 32; ++c) qreg[c] = qbase[c * HW + r] * tg;
    float m = -1e30f, l = 0.f;
    float acc[32];
    #pragma unroll
    for (int c = 0; c < 32; ++c) acc[c] = 0.f;

    for (int dt = 0; dt < DDS; dt += 64) {
        int dcount = min(64, DDS - dt);
        __syncthreads();
        for (int e = threadIdx.x; e < 2048; e += 256) {
            int c = e >> 6, d = e & 63;
            float kv = 0.f, vv = 0.f;
            if (d < dcount) {
                kv = kbase[c * DDS + dt + d];
                vv = vbase[c * DDS + dt + d];
            }
            KT[c][d] = kv;
            VT[c][d] = vv;
        }
        __syncthreads();
        for (int j0 = 0; j0 < dcount; j0 += 16) {
            int jc = min(16, dcount - j0);
            float lg[16];
            #pragma unroll
            for (int j = 0; j < 16; ++j) lg[j] = 0.f;
            #pragma unroll
            for (int c = 0; c < 32; ++c) {
                float qc = qreg[c];
                const float4* kp = (const float4*)&KT[c][j0];
                #pragma unroll
                for (int j4 = 0; j4 < 4; ++j4) {
                    float4 kv = kp[j4];
                    lg[j4 * 4 + 0] = fmaf(qc, kv.x, lg[j4 * 4 + 0]);
                    lg[j4 * 4 + 1] = fmaf(qc, kv.y, lg[j4 * 4 + 1]);
                    lg[j4 * 4 + 2] = fmaf(qc, kv.z, lg[j4 * 4 + 2]);
                    lg[j4 * 4 + 3] = fmaf(qc, kv.w, lg[j4 * 4 + 3]);
                }
            }
            float mc = -1e30f;
            for (int j = 0; j < jc; ++j) mc = fmaxf(mc, lg[j]);
            if (mc > m) {
                float sc = __expf(m - mc);
                l *= sc;
                #pragma unroll
                for (int c = 0; c < 32; ++c) acc[c] *= sc;
                m = mc;
            }
            float p[16];
            float ls = 0.f;
            for (int j = 0; j < 16; ++j) {
                float pv = (j < jc) ? __expf(lg[j] - m) : 0.f;
                p[j] = pv;
                ls += pv;
            }
            l += ls;
            #pragma unroll
            for (int c = 0; c < 32; ++c) {
                const float4* vp = (const float4*)&VT[c][j0];
                float s = acc[c];
                #pragma unroll
                for (int j4 = 0; j4 < 4; ++j4) {
                    float4 vv = vp[j4];
                    s = fmaf(p[j4 * 4 + 0], vv.x, s);
                    s = fmaf(p[j4 * 4 + 1], vv.y, s);
                    s = fmaf(p[j4 * 4 + 2], vv.z, s);
                    s = fmaf(p[j4 * 4 + 3], vv.w, s);
                }
                acc[c] = s;
            }
        }
    }
    if (valid) {
        float inv = 1.f / l;
        float* abase = a + (size_t)ng * 32 * HW;
        #pragma unroll
        for (int c = 0; c < 32; ++c) abase[c * HW + row] = acc[c] * inv;
    }
}

// ---------------- kernel 4: MFMA gates + LSTM combine ----------------
__global__ __launch_bounds__(256) void k_gates_mfma(
        const float* __restrict__ xx, const float* __restrict__ h0,
        const float* __restrict__ c0, const float* __restrict__ a,
        const unsigned short* __restrict__ apg2, const unsigned short* __restrict__ apg1,
        const float* __restrict__ bi, const float* __restrict__ bf_,
        const float* __restrict__ bg, const float* __restrict__ bo,
        float* __restrict__ out) {
    int bid = blockIdx.x;
    int n = bid / 72, rem = bid % 72;
    int g = rem / 9, yt = rem % 9;
    __shared__ bvec8 smx[1824];
    __shared__ bvec8 sma[576];
    int tid = threadIdx.x;
    for (int u = tid; u < 1824; u += 256) {
        int col = u % 38; int t2 = u / 38;
        int icb = t2 % 8; int rr = t2 / 8;
        int y = yt * 4 - 1 + rr, cx = col - 1;
        union { unsigned short us[8]; bvec8 v; } pk;
        if (y >= 0 && y < 36 && cx >= 0 && cx < 36) {
            const float* src = (icb < 4)
                ? (xx + (size_t)(n * CC + g * 32 + icb * 8) * HW)
                : (h0 + (size_t)(n * CC + g * 32 + (icb - 4) * 8) * HW);
            int off = y * 36 + cx;
            #pragma unroll
            for (int j = 0; j < 8; ++j) pk.us[j] = f2bf(src[(size_t)j * HW + off]);
        } else {
            #pragma unroll
            for (int j = 0; j < 8; ++j) pk.us[j] = 0;
        }
        int s = rr * 38 + col;
        smx[s * 8 + (icb ^ (s & 7))] = pk.v;
    }
    for (int u = tid; u < 576; u += 256) {
        int p = u % 144, cb = u / 144;
        int gp = yt * 144 + p;
        const float* src = a + (size_t)(n * CC + g * 32 + cb * 8) * HW + gp;
        union { unsigned short us[8]; bvec8 v; } pk;
        #pragma unroll
        for (int j = 0; j < 8; ++j) pk.us[j] = f2bf(src[(size_t)j * HW]);
        sma[p * 4 + (cb ^ (p & 3))] = pk.v;
    }
    __syncthreads();
    int lane = tid & 63, w = tid >> 6;
    int b = w & 1, nh = w >> 1;
    int kgrp = lane >> 4, nf0 = nh * 4;
    int sb[5], pl[5];
    #pragma unroll
    for (int jn = 0; jn < 5; ++jn) {
        int p = (nf0 + jn) * 16 + (lane & 15);
        pl[jn] = p;
        sb[jn] = (p / 36) * 38 + (p % 36);
    }
    fvec4 acc[4][5];
    #pragma unroll
    for (int i = 0; i < 4; ++i)
        #pragma unroll
        for (int jn = 0; jn < 5; ++jn)
            acc[i][jn] = fvec4{0.f, 0.f, 0.f, 0.f};
    const bvec8* ap = (const bvec8*)apg2 + ((size_t)g * 144 + b) * 64 + lane;
    for (int s = 0; s < 18; ++s) {
        int kyx = s >> 1, icb = s & 1;
        int ky = kyx / 3, kx = kyx % 3;
        bvec8 a0 = ap[0], a1 = ap[128], a2 = ap[256], a3 = ap[384];
        ap += 512;
        int soff = ky * 38 + kx;
        int ib = icb * 4 + kgrp;
        #pragma unroll
        for (int jn = 0; jn < 5; ++jn) {
            int slot = sb[jn] + soff;
            bvec8 bfr = smx[slot * 8 + (ib ^ (slot & 7))];
            acc[0][jn] = __builtin_amdgcn_mfma_f32_16x16x32_bf16(a0, bfr, acc[0][jn], 0, 0, 0);
            acc[1][jn] = __builtin_amdgcn_mfma_f32_16x16x32_bf16(a1, bfr, acc[1][jn], 0, 0, 0);
            acc[2][jn] = __builtin_amdgcn_mfma_f32_16x16x32_bf16(a2, bfr, acc[2][jn], 0, 0, 0);
            acc[3][jn] = __builtin_amdgcn_mfma_f32_16x16x32_bf16(a3, bfr, acc[3][jn], 0, 0, 0);
        }
    }
    {
        const bvec8* ap1 = (const bvec8*)apg1 + ((size_t)g * 8 + b) * 64 + lane;
        bvec8 a0 = ap1[0], a1 = ap1[128], a2 = ap1[256], a3 = ap1[384];
        #pragma unroll
        for (int jn = 0; jn < 5; ++jn) {
            int p = pl[jn];
            bvec8 bfr = sma[p * 4 + (kgrp ^ (p & 3))];
            acc[0][jn] = __builtin_amdgcn_mfma_f32_16x16x32_bf16(a0, bfr, acc[0][jn], 0, 0, 0);
            acc[1][jn] = __builtin_amdgcn_mfma_f32_16x16x32_bf16(a1, bfr, acc[1][jn], 0, 0, 0);
            acc[2][jn] = __builtin_amdgcn_mfma_f32_16x16x32_bf16(a2, bfr, acc[2][jn], 0, 0, 0);
            acc[3][jn] = __builtin_amdgcn_mfma_f32_16x16x32_bf16(a3, bfr, acc[3][jn], 0, 0, 0);
        }
    }
    #pragma unroll
    for (int jn = 0; jn < 5; ++jn) {
        int gp = yt * 144 + pl[jn];
        #pragma unroll
        for (int r = 0; r < 4; ++r) {
            int cl = b * 16 + kgrp * 4 + r;
            int co = g * 32 + cl;
            float ip   = acc[0][jn][r] + bi[co];
            float fp   = acc[1][jn][r] + bf_[co];
            float gpre = acc[2][jn][r] + bg[co];
            float op   = acc[3][jn][r] + bo[co];
            float iv = sigmoidf_(ip), fv = sigmoidf_(fp);
            float gv = tanhf_(gpre), ov = sigmoidf_(op);
            float cv = fmaf(fv, c0[(size_t)(n * CC + co) * HW + gp], iv * gv);
            out[(size_t)(n * CC + co) * HW + gp] = ov * tanhf_(cv);
        }
    }
}

extern "C" void kernel_launch(void* const* d_in, const int* in_sizes, int n_in,
                              void* d_out, int out_size, void* d_ws, size_t ws_size,
                              hipStream_t stream) {
    const float* x   = (const float*)d_in[0];
    const float* h0  = (const float*)d_in[1];
    const float* c0  = (const float*)d_in[2];
    const float* Wx  = (const float*)d_in[3];
    const float* Wq  = (const float*)d_in[4];
    const float* Wk  = (const float*)d_in[5];
    const float* Wv  = (const float*)d_in[6];
    const float* Wi1 = (const float*)d_in[7];
    const float* Wi2 = (const float*)d_in[8];
    const float* bi  = (const float*)d_in[9];
    const float* Wf1 = (const float*)d_in[10];
    const float* Wf2 = (const float*)d_in[11];
    const float* bf  = (const float*)d_in[12];
    const float* Wg1 = (const float*)d_in[13];
    const float* Wg2 = (const float*)d_in[14];
    const float* bg  = (const float*)d_in[15];
    const float* Wo1 = (const float*)d_in[16];
    const float* Wo2 = (const float*)d_in[17];
    const float* bo  = (const float*)d_in[18];
    const float* tau = (const float*)d_in[19];

    float* ws  = (float*)d_ws;
    float* xx  = ws;
    float* q   = xx + 2654208;
    float* k   = q  + 2654208;
    float* v   = k  + 2367488;
    float* a   = v  + 2367488;
    unsigned short* apq  = (unsigned short*)(a + 2654208);
    unsigned short* apg2 = apq + 442368;
    unsigned short* apg1 = apg2 + 589824;
    float* out = (float*)d_out;

    hipLaunchKernelGGL(k_pack_qkv,   dim3(216), dim3(256), 0, stream, Wq, Wk, Wv, apq);
    hipLaunchKernelGGL(k_pack_gates, dim3(304), dim3(256), 0, stream,
                       Wi2, Wf2, Wg2, Wo2, Wi1, Wf1, Wg1, Wo1, apg2, apg1);
    hipLaunchKernelGGL(k_xx,         dim3(NN * CC), dim3(256), 0, stream, x, Wx, xx);
    hipLaunchKernelGGL(k_qkv_mfma,   dim3(576),  dim3(384), 0, stream, xx, h0, apq, q, k, v);
    hipLaunchKernelGGL(k_attn,       dim3(384),  dim3(256), 0, stream, q, k, v, tau, a);
    hipLaunchKernelGGL(k_gates_mfma, dim3(576),  dim3(256), 0, stream, xx, h0, c0, a,
                       apg2, apg1, bi, bf, bg, bo, out);
}

// Round 3
// 192.675 us; speedup vs baseline: 11.6303x; 4.8149x over previous
//
#include <hip/hip_runtime.h>
#include <math.h>

#define NN  8
#define CIN 128
#define HW  1296
#define CC  256
#define DDS 1156

typedef __attribute__((ext_vector_type(8))) short bvec8;
typedef __attribute__((ext_vector_type(4))) float fvec4;

__device__ __forceinline__ float sigmoidf_(float x) {
    return 1.f / (1.f + __expf(-x));
}
__device__ __forceinline__ float tanhf_(float x) {
    float xa = fminf(fmaxf(x, -15.f), 15.f);
    float e = __expf(2.f * xa);
    return (e - 1.f) / (e + 1.f);
}
__device__ __forceinline__ unsigned short f2bf(float f) {
    unsigned int u = __float_as_uint(f);
    u = (u + 0x7FFFu + ((u >> 16) & 1u)) >> 16;
    return (unsigned short)u;
}

// ---------------- kernel 1: xx = 1x1 conv(x, Wx), no bias (fp32) ----------------
__global__ void k_xx(const float* __restrict__ x, const float* __restrict__ Wx,
                     float* __restrict__ xx) {
    int b  = blockIdx.x;
    int n  = b >> 8, co = b & 255;
    const float* wrow = Wx + co * CIN;
    const float4* xin = (const float4*)(x + n * CIN * HW);
    float4* out = (float4*)(xx + (n * CC + co) * HW);
    for (int wi = threadIdx.x; wi < HW / 4; wi += blockDim.x) {
        float4 s = {0.f, 0.f, 0.f, 0.f};
        #pragma unroll 8
        for (int ci = 0; ci < CIN; ++ci) {
            float w = wrow[ci];
            float4 xv = xin[ci * (HW / 4) + wi];
            s.x = fmaf(w, xv.x, s.x);
            s.y = fmaf(w, xv.y, s.y);
            s.z = fmaf(w, xv.z, s.z);
            s.w = fmaf(w, xv.w, s.w);
        }
        out[wi] = s;
    }
}

// ---------------- weight packing: QKV -> MFMA A-fragments (tau folded into Wq) ----------------
__global__ void k_pack_qkv(const float* __restrict__ Wq, const float* __restrict__ Wk,
                           const float* __restrict__ Wv, const float* __restrict__ tau,
                           unsigned short* __restrict__ apq) {
    int t = blockIdx.x * 256 + threadIdx.x;
    if (t >= 55296) return;
    int lane = t & 63;
    int t2 = t >> 6;
    int mf = t2 % 6, t3 = t2 / 6;
    int s = t3 % 18, g = t3 / 18;
    int kyx = s >> 1, icb = s & 1;
    int ky = kyx / 3, kx = kyx % 3;
    int m = mf * 16 + (lane & 15);
    int conv = m >> 5, cl = m & 31, co = g * 32 + cl;
    int ic0 = icb * 32 + (lane >> 4) * 8;
    const float* W = (conv == 0) ? Wq : (conv == 1 ? Wk : Wv);
    float scale = (conv == 0) ? tau[g] : 1.f;
    union { unsigned short us[8]; bvec8 v; } pk;
    #pragma unroll
    for (int j = 0; j < 8; ++j)
        pk.us[j] = f2bf(W[((co * 64 + ic0 + j) * 3 + ky) * 3 + kx] * scale);
    *(bvec8*)(apq + (size_t)t * 8) = pk.v;
}

__global__ void k_pack_gates(const float* __restrict__ Wi2, const float* __restrict__ Wf2,
                             const float* __restrict__ Wg2, const float* __restrict__ Wo2,
                             const float* __restrict__ Wi1, const float* __restrict__ Wf1,
                             const float* __restrict__ Wg1, const float* __restrict__ Wo1,
                             unsigned short* __restrict__ apg2, unsigned short* __restrict__ apg1) {
    int t = blockIdx.x * 256 + threadIdx.x;
    if (t < 73728) {
        int lane = t & 63;
        int t2 = t >> 6;
        int mf = t2 % 8, t3 = t2 / 8;
        int s = t3 % 18, g = t3 / 18;
        int kyx = s >> 1, icb = s & 1;
        int ky = kyx / 3, kx = kyx % 3;
        int m = mf * 16 + (lane & 15);
        int gate = m >> 5, cl = m & 31, co = g * 32 + cl;
        int ic0 = icb * 32 + (lane >> 4) * 8;
        const float* W = (gate == 0) ? Wi2 : (gate == 1 ? Wf2 : (gate == 2 ? Wg2 : Wo2));
        union { unsigned short us[8]; bvec8 v; } pk;
        #pragma unroll
        for (int j = 0; j < 8; ++j)
            pk.us[j] = f2bf(W[((co * 64 + ic0 + j) * 3 + ky) * 3 + kx]);
        *(bvec8*)(apg2 + (size_t)t * 8) = pk.v;
    } else if (t < 77824) {
        int u = t - 73728;
        int lane = u & 63;
        int t2 = u >> 6;
        int mf = t2 % 8, g = t2 / 8;
        int m = mf * 16 + (lane & 15);
        int gate = m >> 5, cl = m & 31, co = g * 32 + cl;
        int k0 = (lane >> 4) * 8;
        const float* W = (gate == 0) ? Wi1 : (gate == 1 ? Wf1 : (gate == 2 ? Wg1 : Wo1));
        union { unsigned short us[8]; bvec8 v; } pk;
        #pragma unroll
        for (int j = 0; j < 8; ++j)
            pk.us[j] = f2bf(W[co * 32 + k0 + j]);
        *(bvec8*)(apg1 + (size_t)u * 8) = pk.v;
    }
}

// ---------------- kernel 2: MFMA grouped 3x3 conv -> qT, kT, v (bf16, attn-ready) ----------------
// qT: [ng][1296][32] bf16 (tau already folded via pack)
// kT: [ng][1156][32] bf16
// vB: [ng][32][1160] bf16 (row-padded for 16B-aligned reads)
__global__ __launch_bounds__(384) void k_qkv_mfma(
        const float* __restrict__ xx, const float* __restrict__ h0,
        const unsigned short* __restrict__ apq,
        unsigned short* __restrict__ qT, unsigned short* __restrict__ kT,
        unsigned short* __restrict__ vB) {
    int bid = blockIdx.x;
    int n = bid / 72, rem = bid % 72;
    int g = rem / 9, yt = rem % 9;
    __shared__ bvec8 sm[1824];
    int tid = threadIdx.x;
    for (int u = tid; u < 1824; u += 384) {
        int col = u % 38; int t2 = u / 38;
        int icb = t2 % 8; int rr = t2 / 8;
        int y = yt * 4 - 1 + rr, cx = col - 1;
        union { unsigned short us[8]; bvec8 v; } pk;
        if (y >= 0 && y < 36 && cx >= 0 && cx < 36) {
            const float* src = (icb < 4)
                ? (xx + (size_t)(n * CC + g * 32 + icb * 8) * HW)
                : (h0 + (size_t)(n * CC + g * 32 + (icb - 4) * 8) * HW);
            int off = y * 36 + cx;
            #pragma unroll
            for (int j = 0; j < 8; ++j) pk.us[j] = f2bf(src[(size_t)j * HW + off]);
        } else {
            #pragma unroll
            for (int j = 0; j < 8; ++j) pk.us[j] = 0;
        }
        int s = rr * 38 + col;
        sm[s * 8 + (icb ^ (s & 7))] = pk.v;
    }
    __syncthreads();
    int lane = tid & 63, w = tid >> 6;
    int mg = w % 3, nh = w / 3;
    int kgrp = lane >> 4;
    int nf0 = nh * 4;
    int sb[5], pl[5];
    #pragma unroll
    for (int jn = 0; jn < 5; ++jn) {
        int p = (nf0 + jn) * 16 + (lane & 15);
        pl[jn] = p;
        sb[jn] = (p / 36) * 38 + (p % 36);
    }
    fvec4 acc[2][5];
    #pragma unroll
    for (int i = 0; i < 2; ++i)
        #pragma unroll
        for (int jn = 0; jn < 5; ++jn)
            acc[i][jn] = fvec4{0.f, 0.f, 0.f, 0.f};
    const bvec8* ap = (const bvec8*)apq + (size_t)g * 6912 + mg * 128 + lane;
    for (int s = 0; s < 18; ++s) {
        int kyx = s >> 1, icb = s & 1;
        int ky = kyx / 3, kx = kyx % 3;
        bvec8 a0 = ap[0], a1 = ap[64];
        ap += 384;
        int soff = ky * 38 + kx;
        int ib = icb * 4 + kgrp;
        #pragma unroll
        for (int jn = 0; jn < 5; ++jn) {
            int slot = sb[jn] + soff;
            bvec8 bfr = sm[slot * 8 + (ib ^ (slot & 7))];
            acc[0][jn] = __builtin_amdgcn_mfma_f32_16x16x32_bf16(a0, bfr, acc[0][jn], 0, 0, 0);
            acc[1][jn] = __builtin_amdgcn_mfma_f32_16x16x32_bf16(a1, bfr, acc[1][jn], 0, 0, 0);
        }
    }
    int ngb = n * 8 + g;
    unsigned short* qTg = qT + (size_t)ngb * 41472;
    unsigned short* kTg = kT + (size_t)ngb * 36992;
    unsigned short* vBg = vB + (size_t)ngb * 37120;
    #pragma unroll
    for (int i = 0; i < 2; ++i) {
        int mf = mg * 2 + i;
        int m0 = mf * 16 + kgrp * 4;
        int conv = m0 >> 5, c0 = m0 & 31;
        #pragma unroll
        for (int jn = 0; jn < 5; ++jn) {
            int gp = yt * 144 + pl[jn];
            int py = gp / 36, px = gp % 36;
            if (conv == 0) {
                union { unsigned short us[4]; unsigned long long u; } pk;
                #pragma unroll
                for (int r = 0; r < 4; ++r) pk.us[r] = f2bf(acc[i][jn][r]);
                *(unsigned long long*)(qTg + (size_t)gp * 32 + c0) = pk.u;
            } else if (py >= 1 && py <= 34 && px >= 1 && px <= 34) {
                int dpix = (py - 1) * 34 + (px - 1);
                if (conv == 1) {
                    union { unsigned short us[4]; unsigned long long u; } pk;
                    #pragma unroll
                    for (int r = 0; r < 4; ++r) pk.us[r] = f2bf(acc[i][jn][r]);
                    *(unsigned long long*)(kTg + (size_t)dpix * 32 + c0) = pk.u;
                } else {
                    #pragma unroll
                    for (int r = 0; r < 4; ++r)
                        vBg[(size_t)(c0 + r) * 1160 + dpix] = f2bf(acc[i][jn][r]);
                }
            }
        }
    }
}

// ---------------- kernel 3: MFMA flash attention ----------------
// block = (ng, 4 q-blocks of 16); wave = one 16-q block; no __syncthreads.
__global__ __launch_bounds__(256) void k_attn_mfma(
        const unsigned short* __restrict__ qT, const unsigned short* __restrict__ kT,
        const unsigned short* __restrict__ vB, float* __restrict__ a) {
    int bid = blockIdx.x;
    int ng = bid / 21, bt = bid % 21;
    int tid = threadIdx.x;
    int w = tid >> 6, l = tid & 63;
    int qblk = bt * 4 + w;
    bool qvalid = qblk < 81;
    int qb = qvalid ? qblk : 80;
    int ln = l & 15, g = l >> 4;
    __shared__ unsigned short sP[4][640];   // per-wave [16 q][40] (32 d + pad)
    const unsigned short* qTg = qT + (size_t)ng * 41472;
    const unsigned short* kTg = kT + (size_t)ng * 36992;
    const unsigned short* vBg = vB + (size_t)ng * 37120;
    bvec8 qf = *(const bvec8*)(qTg + (size_t)(qb * 16 + ln) * 32 + g * 8);
    fvec4 acc0 = {0.f, 0.f, 0.f, 0.f}, acc1 = {0.f, 0.f, 0.f, 0.f};
    fvec4 zero = {0.f, 0.f, 0.f, 0.f};
    float m = -1e30f, lp = 0.f;
    for (int dt = 0; dt < DDS; dt += 32) {
        int d0 = dt + ln;
        bvec8 kA0 = *(const bvec8*)(kTg + (size_t)min(d0, 1155) * 32 + g * 8);
        bvec8 kA1 = *(const bvec8*)(kTg + (size_t)min(d0 + 16, 1155) * 32 + g * 8);
        bvec8 vA0 = *(const bvec8*)(vBg + (size_t)ln * 1160 + dt + g * 8);
        bvec8 vA1 = *(const bvec8*)(vBg + (size_t)(16 + ln) * 1160 + dt + g * 8);
        fvec4 s0 = __builtin_amdgcn_mfma_f32_16x16x32_bf16(kA0, qf, zero, 0, 0, 0);
        fvec4 s1 = __builtin_amdgcn_mfma_f32_16x16x32_bf16(kA1, qf, zero, 0, 0, 0);
        if (dt + 32 > DDS) {          // tail tile: only d 1152..1155 valid (g==0, s0)
            if (g > 0) { s0[0] = s0[1] = s0[2] = s0[3] = -1e30f; }
            s1[0] = s1[1] = s1[2] = s1[3] = -1e30f;
        }
        float tm = fmaxf(fmaxf(fmaxf(s0[0], s0[1]), fmaxf(s0[2], s0[3])),
                         fmaxf(fmaxf(s1[0], s1[1]), fmaxf(s1[2], s1[3])));
        tm = fmaxf(tm, __shfl_xor(tm, 16, 64));
        tm = fmaxf(tm, __shfl_xor(tm, 32, 64));
        float mn = fmaxf(m, tm);
        float sc = __expf(m - mn);
        m = mn;
        lp *= sc;
        #pragma unroll
        for (int r = 0; r < 4; ++r) { acc0[r] *= sc; acc1[r] *= sc; }
        float p[8];
        #pragma unroll
        for (int r = 0; r < 4; ++r) {
            p[r]     = __expf(s0[r] - mn);
            p[4 + r] = __expf(s1[r] - mn);
        }
        lp += ((p[0] + p[1]) + (p[2] + p[3])) + ((p[4] + p[5]) + (p[6] + p[7]));
        union { unsigned short us[4]; unsigned long long u; } pk0, pk1;
        #pragma unroll
        for (int r = 0; r < 4; ++r) { pk0.us[r] = f2bf(p[r]); pk1.us[r] = f2bf(p[4 + r]); }
        *(unsigned long long*)&sP[w][ln * 40 + g * 4]      = pk0.u;
        *(unsigned long long*)&sP[w][ln * 40 + 16 + g * 4] = pk1.u;
        bvec8 pB = *(bvec8*)&sP[w][ln * 40 + g * 8];
        acc0 = __builtin_amdgcn_mfma_f32_16x16x32_bf16(vA0, pB, acc0, 0, 0, 0);
        acc1 = __builtin_amdgcn_mfma_f32_16x16x32_bf16(vA1, pB, acc1, 0, 0, 0);
    }
    float lt = lp;
    lt += __shfl_xor(lt, 16, 64);
    lt += __shfl_xor(lt, 32, 64);
    float inv = 1.f / lt;
    if (qvalid) {
        int qpos = qblk * 16 + ln;
        float* ag = a + (size_t)ng * 41472;
        #pragma unroll
        for (int r = 0; r < 4; ++r) {
            ag[(size_t)(g * 4 + r) * HW + qpos]      = acc0[r] * inv;
            ag[(size_t)(16 + g * 4 + r) * HW + qpos] = acc1[r] * inv;
        }
    }
}

// ---------------- kernel 4: MFMA gates + LSTM combine ----------------
__global__ __launch_bounds__(256) void k_gates_mfma(
        const float* __restrict__ xx, const float* __restrict__ h0,
        const float* __restrict__ c0, const float* __restrict__ a,
        const unsigned short* __restrict__ apg2, const unsigned short* __restrict__ apg1,
        const float* __restrict__ bi, const float* __restrict__ bf_,
        const float* __restrict__ bg, const float* __restrict__ bo,
        float* __restrict__ out) {
    int bid = blockIdx.x;
    int n = bid / 72, rem = bid % 72;
    int g = rem / 9, yt = rem % 9;
    __shared__ bvec8 smx[1824];
    __shared__ bvec8 sma[576];
    int tid = threadIdx.x;
    for (int u = tid; u < 1824; u += 256) {
        int col = u % 38; int t2 = u / 38;
        int icb = t2 % 8; int rr = t2 / 8;
        int y = yt * 4 - 1 + rr, cx = col - 1;
        union { unsigned short us[8]; bvec8 v; } pk;
        if (y >= 0 && y < 36 && cx >= 0 && cx < 36) {
            const float* src = (icb < 4)
                ? (xx + (size_t)(n * CC + g * 32 + icb * 8) * HW)
                : (h0 + (size_t)(n * CC + g * 32 + (icb - 4) * 8) * HW);
            int off = y * 36 + cx;
            #pragma unroll
            for (int j = 0; j < 8; ++j) pk.us[j] = f2bf(src[(size_t)j * HW + off]);
        } else {
            #pragma unroll
            for (int j = 0; j < 8; ++j) pk.us[j] = 0;
        }
        int s = rr * 38 + col;
        smx[s * 8 + (icb ^ (s & 7))] = pk.v;
    }
    for (int u = tid; u < 576; u += 256) {
        int p = u % 144, cb = u / 144;
        int gp = yt * 144 + p;
        const float* src = a + (size_t)(n * CC + g * 32 + cb * 8) * HW + gp;
        union { unsigned short us[8]; bvec8 v; } pk;
        #pragma unroll
        for (int j = 0; j < 8; ++j) pk.us[j] = f2bf(src[(size_t)j * HW]);
        sma[p * 4 + (cb ^ (p & 3))] = pk.v;
    }
    __syncthreads();
    int lane = tid & 63, w = tid >> 6;
    int b = w & 1, nh = w >> 1;
    int kgrp = lane >> 4, nf0 = nh * 4;
    int sb[5], pl[5];
    #pragma unroll
    for (int jn = 0; jn < 5; ++jn) {
        int p = (nf0 + jn) * 16 + (lane & 15);
        pl[jn] = p;
        sb[jn] = (p / 36) * 38 + (p % 36);
    }
    fvec4 acc[4][5];
    #pragma unroll
    for (int i = 0; i < 4; ++i)
        #pragma unroll
        for (int jn = 0; jn < 5; ++jn)
            acc[i][jn] = fvec4{0.f, 0.f, 0.f, 0.f};
    const bvec8* ap = (const bvec8*)apg2 + ((size_t)g * 144 + b) * 64 + lane;
    for (int s = 0; s < 18; ++s) {
        int kyx = s >> 1, icb = s & 1;
        int ky = kyx / 3, kx = kyx % 3;
        bvec8 a0 = ap[0], a1 = ap[128], a2 = ap[256], a3 = ap[384];
        ap += 512;
        int soff = ky * 38 + kx;
        int ib = icb * 4 + kgrp;
        #pragma unroll
        for (int jn = 0; jn < 5; ++jn) {
            int slot = sb[jn] + soff;
            bvec8 bfr = smx[slot * 8 + (ib ^ (slot & 7))];
            acc[0][jn] = __builtin_amdgcn_mfma_f32_16x16x32_bf16(a0, bfr, acc[0][jn], 0, 0, 0);
            acc[1][jn] = __builtin_amdgcn_mfma_f32_16x16x32_bf16(a1, bfr, acc[1][jn], 0, 0, 0);
            acc[2][jn] = __builtin_amdgcn_mfma_f32_16x16x32_bf16(a2, bfr, acc[2][jn], 0, 0, 0);
            acc[3][jn] = __builtin_amdgcn_mfma_f32_16x16x32_bf16(a3, bfr, acc[3][jn], 0, 0, 0);
        }
    }
    {
        const bvec8* ap1 = (const bvec8*)apg1 + ((size_t)g * 8 + b) * 64 + lane;
        bvec8 a0 = ap1[0], a1 = ap1[128], a2 = ap1[256], a3 = ap1[384];
        #pragma unroll
        for (int jn = 0; jn < 5; ++jn) {
            int p = pl[jn];
            bvec8 bfr = sma[p * 4 + (kgrp ^ (p & 3))];
            acc[0][jn] = __builtin_amdgcn_mfma_f32_16x16x32_bf16(a0, bfr, acc[0][jn], 0, 0, 0);
            acc[1][jn] = __builtin_amdgcn_mfma_f32_16x16x32_bf16(a1, bfr, acc[1][jn], 0, 0, 0);
            acc[2][jn] = __builtin_amdgcn_mfma_f32_16x16x32_bf16(a2, bfr, acc[2][jn], 0, 0, 0);
            acc[3][jn] = __builtin_amdgcn_mfma_f32_16x16x32_bf16(a3, bfr, acc[3][jn], 0, 0, 0);
        }
    }
    #pragma unroll
    for (int jn = 0; jn < 5; ++jn) {
        int gp = yt * 144 + pl[jn];
        #pragma unroll
        for (int r = 0; r < 4; ++r) {
            int cl = b * 16 + kgrp * 4 + r;
            int co = g * 32 + cl;
            float ip   = acc[0][jn][r] + bi[co];
            float fp   = acc[1][jn][r] + bf_[co];
            float gpre = acc[2][jn][r] + bg[co];
            float op   = acc[3][jn][r] + bo[co];
            float iv = sigmoidf_(ip), fv = sigmoidf_(fp);
            float gv = tanhf_(gpre), ov = sigmoidf_(op);
            float cv = fmaf(fv, c0[(size_t)(n * CC + co) * HW + gp], iv * gv);
            out[(size_t)(n * CC + co) * HW + gp] = ov * tanhf_(cv);
        }
    }
}

extern "C" void kernel_launch(void* const* d_in, const int* in_sizes, int n_in,
                              void* d_out, int out_size, void* d_ws, size_t ws_size,
                              hipStream_t stream) {
    const float* x   = (const float*)d_in[0];
    const float* h0  = (const float*)d_in[1];
    const float* c0  = (const float*)d_in[2];
    const float* Wx  = (const float*)d_in[3];
    const float* Wq  = (const float*)d_in[4];
    const float* Wk  = (const float*)d_in[5];
    const float* Wv  = (const float*)d_in[6];
    const float* Wi1 = (const float*)d_in[7];
    const float* Wi2 = (const float*)d_in[8];
    const float* bi  = (const float*)d_in[9];
    const float* Wf1 = (const float*)d_in[10];
    const float* Wf2 = (const float*)d_in[11];
    const float* bf  = (const float*)d_in[12];
    const float* Wg1 = (const float*)d_in[13];
    const float* Wg2 = (const float*)d_in[14];
    const float* bg  = (const float*)d_in[15];
    const float* Wo1 = (const float*)d_in[16];
    const float* Wo2 = (const float*)d_in[17];
    const float* bo  = (const float*)d_in[18];
    const float* tau = (const float*)d_in[19];

    float* ws  = (float*)d_ws;
    float* xx  = ws;                                        // 2,654,208 f32
    float* a   = xx + 2654208;                              // 2,654,208 f32
    unsigned short* qT   = (unsigned short*)(a + 2654208);  // 2,654,208 bf16
    unsigned short* kT   = qT + 2654208;                    // 2,367,488 bf16
    unsigned short* vB   = kT + 2367488;                    // 2,375,744 bf16 (padded)
    unsigned short* apq  = vB + 2375744;                    // 442,368 bf16
    unsigned short* apg2 = apq + 442368;                    // 589,824 bf16
    unsigned short* apg1 = apg2 + 589824;                   // 32,768 bf16
    float* out = (float*)d_out;

    hipLaunchKernelGGL(k_pack_qkv,   dim3(216), dim3(256), 0, stream, Wq, Wk, Wv, tau, apq);
    hipLaunchKernelGGL(k_pack_gates, dim3(304), dim3(256), 0, stream,
                       Wi2, Wf2, Wg2, Wo2, Wi1, Wf1, Wg1, Wo1, apg2, apg1);
    hipLaunchKernelGGL(k_xx,         dim3(NN * CC), dim3(256), 0, stream, x, Wx, xx);
    hipLaunchKernelGGL(k_qkv_mfma,   dim3(576),  dim3(384), 0, stream, xx, h0, apq, qT, kT, vB);
    hipLaunchKernelGGL(k_attn_mfma,  dim3(1344), dim3(256), 0, stream, qT, kT, vB, a);
    hipLaunchKernelGGL(k_gates_mfma, dim3(576),  dim3(256), 0, stream, xx, h0, c0, a,
                       apg2, apg1, bi, bf, bg, bo, out);
}

// Round 4
// 136.337 us; speedup vs baseline: 16.4364x; 1.4132x over previous
//
#include <hip/hip_runtime.h>
#include <math.h>

#define NN  8
#define CIN 128
#define HW  1296
#define CC  256
#define DDS 1156

typedef __attribute__((ext_vector_type(8))) short bvec8;
typedef __attribute__((ext_vector_type(4))) float fvec4;

__device__ __forceinline__ float sigmoidf_(float x) {
    return 1.f / (1.f + __expf(-x));
}
__device__ __forceinline__ float tanhf_(float x) {
    float xa = fminf(fmaxf(x, -15.f), 15.f);
    float e = __expf(2.f * xa);
    return (e - 1.f) / (e + 1.f);
}
__device__ __forceinline__ unsigned short f2bf(float f) {
    unsigned int u = __float_as_uint(f);
    u = (u + 0x7FFFu + ((u >> 16) & 1u)) >> 16;
    return (unsigned short)u;
}

// ---------------- kernel 0: prep — convert x/h0 to interleaved bf16 + pack all weights ----------------
// xb : [n][icb:16][p:1296][8]   (x bf16)
// h0b: [n][ocb:32][p:1296][8]   (h0 bf16)
// apx: [s:4][mf:16][64][8]      (Wx A-frags)
// apq: [g][s:18][mf:6][64][8]   (Wq*tau,Wk,Wv A-frags)
// apg2:[g][s:18][mf:8][64][8]   (gate 3x3 A-frags)
// apg1:[g][mf:8][64][8]         (gate 1x1 A-frags)
__global__ void k_prep(const float* __restrict__ x, const float* __restrict__ h0,
                       const float* __restrict__ Wx,
                       const float* __restrict__ Wq, const float* __restrict__ Wk,
                       const float* __restrict__ Wv, const float* __restrict__ tau,
                       const float* __restrict__ Wi2, const float* __restrict__ Wf2,
                       const float* __restrict__ Wg2, const float* __restrict__ Wo2,
                       const float* __restrict__ Wi1, const float* __restrict__ Wf1,
                       const float* __restrict__ Wg1, const float* __restrict__ Wo1,
                       unsigned short* __restrict__ xb, unsigned short* __restrict__ h0b,
                       unsigned short* __restrict__ apx, unsigned short* __restrict__ apq,
                       unsigned short* __restrict__ apg2, unsigned short* __restrict__ apg1) {
    int t = blockIdx.x * 256 + threadIdx.x;
    union { unsigned short us[8]; bvec8 v; } pk;
    if (t < 165888) {                       // x convert
        int p = t % 1296; int t2 = t / 1296;
        int icb = t2 % 16, n = t2 / 16;
        #pragma unroll
        for (int j = 0; j < 8; ++j)
            pk.us[j] = f2bf(x[(size_t)(n * CIN + icb * 8 + j) * HW + p]);
        *(bvec8*)(xb + (size_t)t * 8) = pk.v;
    } else if (t < 497664) {                // h0 convert
        int u = t - 165888;
        int p = u % 1296; int t2 = u / 1296;
        int ocb = t2 % 32, n = t2 / 32;
        #pragma unroll
        for (int j = 0; j < 8; ++j)
            pk.us[j] = f2bf(h0[(size_t)(n * CC + ocb * 8 + j) * HW + p]);
        *(bvec8*)(h0b + (size_t)u * 8) = pk.v;
    } else if (t < 552960) {                // apq
        int u = t - 497664;
        int lane = u & 63;
        int t2 = u >> 6;
        int mf = t2 % 6, t3 = t2 / 6;
        int s = t3 % 18, g = t3 / 18;
        int kyx = s >> 1, icb = s & 1;
        int ky = kyx / 3, kx = kyx % 3;
        int m = mf * 16 + (lane & 15);
        int conv = m >> 5, cl = m & 31, co = g * 32 + cl;
        int ic0 = icb * 32 + (lane >> 4) * 8;
        const float* W = (conv == 0) ? Wq : (conv == 1 ? Wk : Wv);
        float scale = (conv == 0) ? tau[g] : 1.f;
        #pragma unroll
        for (int j = 0; j < 8; ++j)
            pk.us[j] = f2bf(W[((co * 64 + ic0 + j) * 3 + ky) * 3 + kx] * scale);
        *(bvec8*)(apq + (size_t)u * 8) = pk.v;
    } else if (t < 557056) {                // apx
        int u = t - 552960;
        int lane = u & 63;
        int t2 = u >> 6;
        int mf = t2 % 16, s = t2 / 16;
        int co = mf * 16 + (lane & 15);
        int k0 = s * 32 + (lane >> 4) * 8;
        #pragma unroll
        for (int j = 0; j < 8; ++j)
            pk.us[j] = f2bf(Wx[co * CIN + k0 + j]);
        *(bvec8*)(apx + (size_t)u * 8) = pk.v;
    } else if (t < 630784) {                // apg2
        int u = t - 557056;
        int lane = u & 63;
        int t2 = u >> 6;
        int mf = t2 % 8, t3 = t2 / 8;
        int s = t3 % 18, g = t3 / 18;
        int kyx = s >> 1, icb = s & 1;
        int ky = kyx / 3, kx = kyx % 3;
        int m = mf * 16 + (lane & 15);
        int gate = m >> 5, cl = m & 31, co = g * 32 + cl;
        int ic0 = icb * 32 + (lane >> 4) * 8;
        const float* W = (gate == 0) ? Wi2 : (gate == 1 ? Wf2 : (gate == 2 ? Wg2 : Wo2));
        #pragma unroll
        for (int j = 0; j < 8; ++j)
            pk.us[j] = f2bf(W[((co * 64 + ic0 + j) * 3 + ky) * 3 + kx]);
        *(bvec8*)(apg2 + (size_t)u * 8) = pk.v;
    } else if (t < 634880) {                // apg1
        int u = t - 630784;
        int lane = u & 63;
        int t2 = u >> 6;
        int mf = t2 % 8, g = t2 / 8;
        int m = mf * 16 + (lane & 15);
        int gate = m >> 5, cl = m & 31, co = g * 32 + cl;
        int k0 = (lane >> 4) * 8;
        const float* W = (gate == 0) ? Wi1 : (gate == 1 ? Wf1 : (gate == 2 ? Wg1 : Wo1));
        #pragma unroll
        for (int j = 0; j < 8; ++j)
            pk.us[j] = f2bf(W[co * 32 + k0 + j]);
        *(bvec8*)(apg1 + (size_t)u * 8) = pk.v;
    }
}

// ---------------- kernel 1: xx = Wx·x as MFMA GEMM, interleaved bf16 out ----------------
// block = (n, 48-pixel chunk); 4 waves, wave w covers channels w*64..w*64+63
__global__ __launch_bounds__(256) void k_xx_mfma(
        const unsigned short* __restrict__ xb, const unsigned short* __restrict__ apx,
        unsigned short* __restrict__ xxb) {
    int bid = blockIdx.x;
    int n = bid / 27, pc = bid % 27;
    int tid = threadIdx.x;
    int w = tid >> 6, lane = tid & 63;
    int ln = lane & 15, kgrp = lane >> 4;
    const bvec8* A = (const bvec8*)apx;
    bvec8 af[4][4];
    #pragma unroll
    for (int s = 0; s < 4; ++s)
        #pragma unroll
        for (int i = 0; i < 4; ++i)
            af[s][i] = A[(s * 16 + w * 4 + i) * 64 + lane];
    fvec4 acc[4][3];
    #pragma unroll
    for (int i = 0; i < 4; ++i)
        #pragma unroll
        for (int jn = 0; jn < 3; ++jn)
            acc[i][jn] = fvec4{0.f, 0.f, 0.f, 0.f};
    #pragma unroll
    for (int s = 0; s < 4; ++s) {
        #pragma unroll
        for (int jn = 0; jn < 3; ++jn) {
            int p = pc * 48 + jn * 16 + ln;
            bvec8 bfr = *(const bvec8*)(xb + ((size_t)(n * 16 + s * 4 + kgrp) * HW + p) * 8);
            #pragma unroll
            for (int i = 0; i < 4; ++i)
                acc[i][jn] = __builtin_amdgcn_mfma_f32_16x16x32_bf16(af[s][i], bfr, acc[i][jn], 0, 0, 0);
        }
    }
    #pragma unroll
    for (int i = 0; i < 4; ++i) {
        int co0 = (w * 4 + i) * 16 + kgrp * 4;
        int icb = co0 >> 3, sub = co0 & 7;
        #pragma unroll
        for (int jn = 0; jn < 3; ++jn) {
            int p = pc * 48 + jn * 16 + ln;
            union { unsigned short us[4]; unsigned long long u; } pk;
            #pragma unroll
            for (int r = 0; r < 4; ++r) pk.us[r] = f2bf(acc[i][jn][r]);
            *(unsigned long long*)(xxb + ((size_t)(n * 32 + icb) * HW + p) * 8 + sub) = pk.u;
        }
    }
}

// ---------------- kernel 2: MFMA grouped 3x3 conv -> qT, kT, vB ----------------
__global__ __launch_bounds__(384) void k_qkv_mfma(
        const unsigned short* __restrict__ xxb, const unsigned short* __restrict__ h0b,
        const unsigned short* __restrict__ apq,
        unsigned short* __restrict__ qT, unsigned short* __restrict__ kT,
        unsigned short* __restrict__ vB) {
    int bid = blockIdx.x;
    int n = bid / 72, rem = bid % 72;
    int g = rem / 9, yt = rem % 9;
    __shared__ bvec8 sm[1824];
    int tid = threadIdx.x;
    for (int u = tid; u < 1824; u += 384) {
        int col = u % 38; int t2 = u / 38;
        int icb = t2 % 8; int rr = t2 / 8;
        int y = yt * 4 - 1 + rr, cx = col - 1;
        bvec8 val = {0, 0, 0, 0, 0, 0, 0, 0};
        if (y >= 0 && y < 36 && cx >= 0 && cx < 36) {
            const unsigned short* src = (icb < 4)
                ? (xxb + ((size_t)(n * 32 + g * 4 + icb) * HW) * 8)
                : (h0b + ((size_t)(n * 32 + g * 4 + icb - 4) * HW) * 8);
            val = *(const bvec8*)(src + (size_t)(y * 36 + cx) * 8);
        }
        int s = rr * 38 + col;
        sm[s * 8 + (icb ^ (s & 7))] = val;
    }
    __syncthreads();
    int lane = tid & 63, w = tid >> 6;
    int mg = w % 3, nh = w / 3;
    int kgrp = lane >> 4;
    int nf0 = nh * 4;
    int sb[5], pl[5];
    #pragma unroll
    for (int jn = 0; jn < 5; ++jn) {
        int p = (nf0 + jn) * 16 + (lane & 15);
        pl[jn] = p;
        sb[jn] = (p / 36) * 38 + (p % 36);
    }
    fvec4 acc[2][5];
    #pragma unroll
    for (int i = 0; i < 2; ++i)
        #pragma unroll
        for (int jn = 0; jn < 5; ++jn)
            acc[i][jn] = fvec4{0.f, 0.f, 0.f, 0.f};
    const bvec8* ap = (const bvec8*)apq + (size_t)g * 6912 + mg * 128 + lane;
    for (int s = 0; s < 18; ++s) {
        int kyx = s >> 1, icb = s & 1;
        int ky = kyx / 3, kx = kyx % 3;
        bvec8 a0 = ap[0], a1 = ap[64];
        ap += 384;
        int soff = ky * 38 + kx;
        int ib = icb * 4 + kgrp;
        #pragma unroll
        for (int jn = 0; jn < 5; ++jn) {
            int slot = sb[jn] + soff;
            bvec8 bfr = sm[slot * 8 + (ib ^ (slot & 7))];
            acc[0][jn] = __builtin_amdgcn_mfma_f32_16x16x32_bf16(a0, bfr, acc[0][jn], 0, 0, 0);
            acc[1][jn] = __builtin_amdgcn_mfma_f32_16x16x32_bf16(a1, bfr, acc[1][jn], 0, 0, 0);
        }
    }
    int ngb = n * 8 + g;
    unsigned short* qTg = qT + (size_t)ngb * 41472;
    unsigned short* kTg = kT + (size_t)ngb * 36992;
    unsigned short* vBg = vB + (size_t)ngb * 37120;
    #pragma unroll
    for (int i = 0; i < 2; ++i) {
        int mf = mg * 2 + i;
        int m0 = mf * 16 + kgrp * 4;
        int conv = m0 >> 5, c0 = m0 & 31;
        #pragma unroll
        for (int jn = 0; jn < 5; ++jn) {
            int gp = yt * 144 + pl[jn];
            int py = gp / 36, px = gp % 36;
            if (conv == 0) {
                union { unsigned short us[4]; unsigned long long u; } pk;
                #pragma unroll
                for (int r = 0; r < 4; ++r) pk.us[r] = f2bf(acc[i][jn][r]);
                *(unsigned long long*)(qTg + (size_t)gp * 32 + c0) = pk.u;
            } else if (py >= 1 && py <= 34 && px >= 1 && px <= 34) {
                int dpix = (py - 1) * 34 + (px - 1);
                if (conv == 1) {
                    union { unsigned short us[4]; unsigned long long u; } pk;
                    #pragma unroll
                    for (int r = 0; r < 4; ++r) pk.us[r] = f2bf(acc[i][jn][r]);
                    *(unsigned long long*)(kTg + (size_t)dpix * 32 + c0) = pk.u;
                } else {
                    #pragma unroll
                    for (int r = 0; r < 4; ++r)
                        vBg[(size_t)(c0 + r) * 1160 + dpix] = f2bf(acc[i][jn][r]);
                }
            }
        }
    }
}

// ---------------- kernel 3: MFMA flash attention -> ab (interleaved bf16) ----------------
__global__ __launch_bounds__(256) void k_attn_mfma(
        const unsigned short* __restrict__ qT, const unsigned short* __restrict__ kT,
        const unsigned short* __restrict__ vB, unsigned short* __restrict__ ab) {
    int bid = blockIdx.x;
    int ng = bid / 21, bt = bid % 21;
    int tid = threadIdx.x;
    int w = tid >> 6, l = tid & 63;
    int qblk = bt * 4 + w;
    bool qvalid = qblk < 81;
    int qb = qvalid ? qblk : 80;
    int ln = l & 15, g = l >> 4;
    __shared__ unsigned short sP[4][640];
    const unsigned short* qTg = qT + (size_t)ng * 41472;
    const unsigned short* kTg = kT + (size_t)ng * 36992;
    const unsigned short* vBg = vB + (size_t)ng * 37120;
    bvec8 qf = *(const bvec8*)(qTg + (size_t)(qb * 16 + ln) * 32 + g * 8);
    fvec4 acc0 = {0.f, 0.f, 0.f, 0.f}, acc1 = {0.f, 0.f, 0.f, 0.f};
    fvec4 zero = {0.f, 0.f, 0.f, 0.f};
    float m = -1e30f, lp = 0.f;
    for (int dt = 0; dt < DDS; dt += 32) {
        int d0 = dt + ln;
        bvec8 kA0 = *(const bvec8*)(kTg + (size_t)min(d0, 1155) * 32 + g * 8);
        bvec8 kA1 = *(const bvec8*)(kTg + (size_t)min(d0 + 16, 1155) * 32 + g * 8);
        bvec8 vA0 = *(const bvec8*)(vBg + (size_t)ln * 1160 + dt + g * 8);
        bvec8 vA1 = *(const bvec8*)(vBg + (size_t)(16 + ln) * 1160 + dt + g * 8);
        fvec4 s0 = __builtin_amdgcn_mfma_f32_16x16x32_bf16(kA0, qf, zero, 0, 0, 0);
        fvec4 s1 = __builtin_amdgcn_mfma_f32_16x16x32_bf16(kA1, qf, zero, 0, 0, 0);
        if (dt + 32 > DDS) {
            if (g > 0) { s0[0] = s0[1] = s0[2] = s0[3] = -1e30f; }
            s1[0] = s1[1] = s1[2] = s1[3] = -1e30f;
        }
        float tm = fmaxf(fmaxf(fmaxf(s0[0], s0[1]), fmaxf(s0[2], s0[3])),
                         fmaxf(fmaxf(s1[0], s1[1]), fmaxf(s1[2], s1[3])));
        tm = fmaxf(tm, __shfl_xor(tm, 16, 64));
        tm = fmaxf(tm, __shfl_xor(tm, 32, 64));
        float mn = fmaxf(m, tm);
        float sc = __expf(m - mn);
        m = mn;
        lp *= sc;
        #pragma unroll
        for (int r = 0; r < 4; ++r) { acc0[r] *= sc; acc1[r] *= sc; }
        float p[8];
        #pragma unroll
        for (int r = 0; r < 4; ++r) {
            p[r]     = __expf(s0[r] - mn);
            p[4 + r] = __expf(s1[r] - mn);
        }
        lp += ((p[0] + p[1]) + (p[2] + p[3])) + ((p[4] + p[5]) + (p[6] + p[7]));
        union { unsigned short us[4]; unsigned long long u; } pk0, pk1;
        #pragma unroll
        for (int r = 0; r < 4; ++r) { pk0.us[r] = f2bf(p[r]); pk1.us[r] = f2bf(p[4 + r]); }
        *(unsigned long long*)&sP[w][ln * 40 + g * 4]      = pk0.u;
        *(unsigned long long*)&sP[w][ln * 40 + 16 + g * 4] = pk1.u;
        bvec8 pB = *(bvec8*)&sP[w][ln * 40 + g * 8];
        acc0 = __builtin_amdgcn_mfma_f32_16x16x32_bf16(vA0, pB, acc0, 0, 0, 0);
        acc1 = __builtin_amdgcn_mfma_f32_16x16x32_bf16(vA1, pB, acc1, 0, 0, 0);
    }
    float lt = lp;
    lt += __shfl_xor(lt, 16, 64);
    lt += __shfl_xor(lt, 32, 64);
    float inv = 1.f / lt;
    if (qvalid) {
        int qpos = qblk * 16 + ln;
        unsigned short* ag = ab + (size_t)ng * 41472;
        int sub = (g & 1) * 4;
        union { unsigned short us[4]; unsigned long long u; } pk0, pk1;
        #pragma unroll
        for (int r = 0; r < 4; ++r) {
            pk0.us[r] = f2bf(acc0[r] * inv);
            pk1.us[r] = f2bf(acc1[r] * inv);
        }
        *(unsigned long long*)(ag + ((size_t)(g >> 1) * HW + qpos) * 8 + sub)       = pk0.u;
        *(unsigned long long*)(ag + ((size_t)(2 + (g >> 1)) * HW + qpos) * 8 + sub) = pk1.u;
    }
}

// ---------------- kernel 4: MFMA gates + LSTM combine ----------------
__global__ __launch_bounds__(256) void k_gates_mfma(
        const unsigned short* __restrict__ xxb, const unsigned short* __restrict__ h0b,
        const float* __restrict__ c0, const unsigned short* __restrict__ ab,
        const unsigned short* __restrict__ apg2, const unsigned short* __restrict__ apg1,
        const float* __restrict__ bi, const float* __restrict__ bf_,
        const float* __restrict__ bg, const float* __restrict__ bo,
        float* __restrict__ out) {
    int bid = blockIdx.x;
    int n = bid / 72, rem = bid % 72;
    int g = rem / 9, yt = rem % 9;
    __shared__ bvec8 smx[1824];
    __shared__ bvec8 sma[576];
    int tid = threadIdx.x;
    for (int u = tid; u < 1824; u += 256) {
        int col = u % 38; int t2 = u / 38;
        int icb = t2 % 8; int rr = t2 / 8;
        int y = yt * 4 - 1 + rr, cx = col - 1;
        bvec8 val = {0, 0, 0, 0, 0, 0, 0, 0};
        if (y >= 0 && y < 36 && cx >= 0 && cx < 36) {
            const unsigned short* src = (icb < 4)
                ? (xxb + ((size_t)(n * 32 + g * 4 + icb) * HW) * 8)
                : (h0b + ((size_t)(n * 32 + g * 4 + icb - 4) * HW) * 8);
            val = *(const bvec8*)(src + (size_t)(y * 36 + cx) * 8);
        }
        int s = rr * 38 + col;
        smx[s * 8 + (icb ^ (s & 7))] = val;
    }
    int ngb = n * 8 + g;
    for (int u = tid; u < 576; u += 256) {
        int p = u % 144, cb = u / 144;
        int gp = yt * 144 + p;
        bvec8 val = *(const bvec8*)(ab + ((size_t)(ngb * 4 + cb) * HW + gp) * 8);
        sma[p * 4 + (cb ^ (p & 3))] = val;
    }
    __syncthreads();
    int lane = tid & 63, w = tid >> 6;
    int b = w & 1, nh = w >> 1;
    int kgrp = lane >> 4, nf0 = nh * 4;
    int sb[5], pl[5];
    #pragma unroll
    for (int jn = 0; jn < 5; ++jn) {
        int p = (nf0 + jn) * 16 + (lane & 15);
        pl[jn] = p;
        sb[jn] = (p / 36) * 38 + (p % 36);
    }
    fvec4 acc[4][5];
    #pragma unroll
    for (int i = 0; i < 4; ++i)
        #pragma unroll
        for (int jn = 0; jn < 5; ++jn)
            acc[i][jn] = fvec4{0.f, 0.f, 0.f, 0.f};
    const bvec8* ap = (const bvec8*)apg2 + ((size_t)g * 144 + b) * 64 + lane;
    for (int s = 0; s < 18; ++s) {
        int kyx = s >> 1, icb = s & 1;
        int ky = kyx / 3, kx = kyx % 3;
        bvec8 a0 = ap[0], a1 = ap[128], a2 = ap[256], a3 = ap[384];
        ap += 512;
        int soff = ky * 38 + kx;
        int ib = icb * 4 + kgrp;
        #pragma unroll
        for (int jn = 0; jn < 5; ++jn) {
            int slot = sb[jn] + soff;
            bvec8 bfr = smx[slot * 8 + (ib ^ (slot & 7))];
            acc[0][jn] = __builtin_amdgcn_mfma_f32_16x16x32_bf16(a0, bfr, acc[0][jn], 0, 0, 0);
            acc[1][jn] = __builtin_amdgcn_mfma_f32_16x16x32_bf16(a1, bfr, acc[1][jn], 0, 0, 0);
            acc[2][jn] = __builtin_amdgcn_mfma_f32_16x16x32_bf16(a2, bfr, acc[2][jn], 0, 0, 0);
            acc[3][jn] = __builtin_amdgcn_mfma_f32_16x16x32_bf16(a3, bfr, acc[3][jn], 0, 0, 0);
        }
    }
    {
        const bvec8* ap1 = (const bvec8*)apg1 + ((size_t)g * 8 + b) * 64 + lane;
        bvec8 a0 = ap1[0], a1 = ap1[128], a2 = ap1[256], a3 = ap1[384];
        #pragma unroll
        for (int jn = 0; jn < 5; ++jn) {
            int p = pl[jn];
            bvec8 bfr = sma[p * 4 + (kgrp ^ (p & 3))];
            acc[0][jn] = __builtin_amdgcn_mfma_f32_16x16x32_bf16(a0, bfr, acc[0][jn], 0, 0, 0);
            acc[1][jn] = __builtin_amdgcn_mfma_f32_16x16x32_bf16(a1, bfr, acc[1][jn], 0, 0, 0);
            acc[2][jn] = __builtin_amdgcn_mfma_f32_16x16x32_bf16(a2, bfr, acc[2][jn], 0, 0, 0);
            acc[3][jn] = __builtin_amdgcn_mfma_f32_16x16x32_bf16(a3, bfr, acc[3][jn], 0, 0, 0);
        }
    }
    #pragma unroll
    for (int jn = 0; jn < 5; ++jn) {
        int gp = yt * 144 + pl[jn];
        #pragma unroll
        for (int r = 0; r < 4; ++r) {
            int cl = b * 16 + kgrp * 4 + r;
            int co = g * 32 + cl;
            float ip   = acc[0][jn][r] + bi[co];
            float fp   = acc[1][jn][r] + bf_[co];
            float gpre = acc[2][jn][r] + bg[co];
            float op   = acc[3][jn][r] + bo[co];
            float iv = sigmoidf_(ip), fv = sigmoidf_(fp);
            float gv = tanhf_(gpre), ov = sigmoidf_(op);
            float cv = fmaf(fv, c0[(size_t)(n * CC + co) * HW + gp], iv * gv);
            out[(size_t)(n * CC + co) * HW + gp] = ov * tanhf_(cv);
        }
    }
}

extern "C" void kernel_launch(void* const* d_in, const int* in_sizes, int n_in,
                              void* d_out, int out_size, void* d_ws, size_t ws_size,
                              hipStream_t stream) {
    const float* x   = (const float*)d_in[0];
    const float* h0  = (const float*)d_in[1];
    const float* c0  = (const float*)d_in[2];
    const float* Wx  = (const float*)d_in[3];
    const float* Wq  = (const float*)d_in[4];
    const float* Wk  = (const float*)d_in[5];
    const float* Wv  = (const float*)d_in[6];
    const float* Wi1 = (const float*)d_in[7];
    const float* Wi2 = (const float*)d_in[8];
    const float* bi  = (const float*)d_in[9];
    const float* Wf1 = (const float*)d_in[10];
    const float* Wf2 = (const float*)d_in[11];
    const float* bf  = (const float*)d_in[12];
    const float* Wg1 = (const float*)d_in[13];
    const float* Wg2 = (const float*)d_in[14];
    const float* bg  = (const float*)d_in[15];
    const float* Wo1 = (const float*)d_in[16];
    const float* Wo2 = (const float*)d_in[17];
    const float* bo  = (const float*)d_in[18];
    const float* tau = (const float*)d_in[19];

    unsigned short* ws  = (unsigned short*)d_ws;
    unsigned short* xb   = ws;                   // 1,327,104
    unsigned short* h0b  = xb   + 1327104;       // 2,654,208
    unsigned short* xxb  = h0b  + 2654208;       // 2,654,208
    unsigned short* ab   = xxb  + 2654208;       // 2,654,208
    unsigned short* qT   = ab   + 2654208;       // 2,654,208
    unsigned short* kT   = qT   + 2654208;       // 2,367,488
    unsigned short* vB   = kT   + 2367488;       // 2,375,744
    unsigned short* apx  = vB   + 2375744;       // 32,768
    unsigned short* apq  = apx  + 32768;         // 442,368
    unsigned short* apg2 = apq  + 442368;        // 589,824
    unsigned short* apg1 = apg2 + 589824;        // 32,768
    float* out = (float*)d_out;

    hipLaunchKernelGGL(k_prep, dim3(2480), dim3(256), 0, stream,
                       x, h0, Wx, Wq, Wk, Wv, tau,
                       Wi2, Wf2, Wg2, Wo2, Wi1, Wf1, Wg1, Wo1,
                       xb, h0b, apx, apq, apg2, apg1);
    hipLaunchKernelGGL(k_xx_mfma,   dim3(216),  dim3(256), 0, stream, xb, apx, xxb);
    hipLaunchKernelGGL(k_qkv_mfma,  dim3(576),  dim3(384), 0, stream, xxb, h0b, apq, qT, kT, vB);
    hipLaunchKernelGGL(k_attn_mfma, dim3(1344), dim3(256), 0, stream, qT, kT, vB, ab);
    hipLaunchKernelGGL(k_gates_mfma,dim3(576),  dim3(256), 0, stream, xxb, h0b, c0, ab,
                       apg2, apg1, bi, bf, bg, bo, out);
}

// Round 5
// 129.951 us; speedup vs baseline: 17.2441x; 1.0491x over previous
//
#include <hip/hip_runtime.h>
#include <math.h>

#define NN  8
#define CIN 128
#define HW  1296
#define CC  256
#define DDS 1156

typedef __attribute__((ext_vector_type(8))) short bvec8;
typedef __attribute__((ext_vector_type(4))) float fvec4;

__device__ __forceinline__ float sigmoidf_(float x) {
    return 1.f / (1.f + __expf(-x));
}
__device__ __forceinline__ float tanhf_(float x) {
    float xa = fminf(fmaxf(x, -15.f), 15.f);
    float e = __expf(2.f * xa);
    return (e - 1.f) / (e + 1.f);
}
__device__ __forceinline__ unsigned short f2bf(float f) {
    unsigned int u = __float_as_uint(f);
    u = (u + 0x7FFFu + ((u >> 16) & 1u)) >> 16;
    return (unsigned short)u;
}
__device__ __forceinline__ unsigned int cvtpk_bf16(float a, float b) {
    unsigned int r;
    asm("v_cvt_pk_bf16_f32 %0, %1, %2" : "=v"(r) : "v"(a), "v"(b));
    return r;   // lo16 = bf16(a), hi16 = bf16(b), RTNE
}

// ---------------- kernel 0: prep — convert x/h0 to interleaved bf16 + pack all weights ----------------
// xb : [n][icb:16][p:1296][8]   (x bf16)
// h0b: [n][ocb:32][p:1296][8]   (h0 bf16)
// apx: [s:4][mf:16][64][8]      (Wx A-frags)
// apq: [g][s:18][mf:6][64][8]   (Wq*tau,Wk,Wv A-frags)
// apg2:[g][s:18][mf:8][64][8]   (gate 3x3 A-frags)
// apg1:[g][mf:8][64][8]         (gate 1x1 A-frags)
__global__ void k_prep(const float* __restrict__ x, const float* __restrict__ h0,
                       const float* __restrict__ Wx,
                       const float* __restrict__ Wq, const float* __restrict__ Wk,
                       const float* __restrict__ Wv, const float* __restrict__ tau,
                       const float* __restrict__ Wi2, const float* __restrict__ Wf2,
                       const float* __restrict__ Wg2, const float* __restrict__ Wo2,
                       const float* __restrict__ Wi1, const float* __restrict__ Wf1,
                       const float* __restrict__ Wg1, const float* __restrict__ Wo1,
                       unsigned short* __restrict__ xb, unsigned short* __restrict__ h0b,
                       unsigned short* __restrict__ apx, unsigned short* __restrict__ apq,
                       unsigned short* __restrict__ apg2, unsigned short* __restrict__ apg1) {
    int t = blockIdx.x * 256 + threadIdx.x;
    union { unsigned short us[8]; bvec8 v; } pk;
    if (t < 165888) {                       // x convert
        int p = t % 1296; int t2 = t / 1296;
        int icb = t2 % 16, n = t2 / 16;
        #pragma unroll
        for (int j = 0; j < 8; ++j)
            pk.us[j] = f2bf(x[(size_t)(n * CIN + icb * 8 + j) * HW + p]);
        *(bvec8*)(xb + (size_t)t * 8) = pk.v;
    } else if (t < 497664) {                // h0 convert
        int u = t - 165888;
        int p = u % 1296; int t2 = u / 1296;
        int ocb = t2 % 32, n = t2 / 32;
        #pragma unroll
        for (int j = 0; j < 8; ++j)
            pk.us[j] = f2bf(h0[(size_t)(n * CC + ocb * 8 + j) * HW + p]);
        *(bvec8*)(h0b + (size_t)u * 8) = pk.v;
    } else if (t < 552960) {                // apq
        int u = t - 497664;
        int lane = u & 63;
        int t2 = u >> 6;
        int mf = t2 % 6, t3 = t2 / 6;
        int s = t3 % 18, g = t3 / 18;
        int kyx = s >> 1, icb = s & 1;
        int ky = kyx / 3, kx = kyx % 3;
        int m = mf * 16 + (lane & 15);
        int conv = m >> 5, cl = m & 31, co = g * 32 + cl;
        int ic0 = icb * 32 + (lane >> 4) * 8;
        const float* W = (conv == 0) ? Wq : (conv == 1 ? Wk : Wv);
        float scale = (conv == 0) ? tau[g] : 1.f;
        #pragma unroll
        for (int j = 0; j < 8; ++j)
            pk.us[j] = f2bf(W[((co * 64 + ic0 + j) * 3 + ky) * 3 + kx] * scale);
        *(bvec8*)(apq + (size_t)u * 8) = pk.v;
    } else if (t < 557056) {                // apx
        int u = t - 552960;
        int lane = u & 63;
        int t2 = u >> 6;
        int mf = t2 % 16, s = t2 / 16;
        int co = mf * 16 + (lane & 15);
        int k0 = s * 32 + (lane >> 4) * 8;
        #pragma unroll
        for (int j = 0; j < 8; ++j)
            pk.us[j] = f2bf(Wx[co * CIN + k0 + j]);
        *(bvec8*)(apx + (size_t)u * 8) = pk.v;
    } else if (t < 630784) {                // apg2
        int u = t - 557056;
        int lane = u & 63;
        int t2 = u >> 6;
        int mf = t2 % 8, t3 = t2 / 8;
        int s = t3 % 18, g = t3 / 18;
        int kyx = s >> 1, icb = s & 1;
        int ky = kyx / 3, kx = kyx % 3;
        int m = mf * 16 + (lane & 15);
        int gate = m >> 5, cl = m & 31, co = g * 32 + cl;
        int ic0 = icb * 32 + (lane >> 4) * 8;
        const float* W = (gate == 0) ? Wi2 : (gate == 1 ? Wf2 : (gate == 2 ? Wg2 : Wo2));
        #pragma unroll
        for (int j = 0; j < 8; ++j)
            pk.us[j] = f2bf(W[((co * 64 + ic0 + j) * 3 + ky) * 3 + kx]);
        *(bvec8*)(apg2 + (size_t)u * 8) = pk.v;
    } else if (t < 634880) {                // apg1
        int u = t - 630784;
        int lane = u & 63;
        int t2 = u >> 6;
        int mf = t2 % 8, g = t2 / 8;
        int m = mf * 16 + (lane & 15);
        int gate = m >> 5, cl = m & 31, co = g * 32 + cl;
        int k0 = (lane >> 4) * 8;
        const float* W = (gate == 0) ? Wi1 : (gate == 1 ? Wf1 : (gate == 2 ? Wg1 : Wo1));
        #pragma unroll
        for (int j = 0; j < 8; ++j)
            pk.us[j] = f2bf(W[co * 32 + k0 + j]);
        *(bvec8*)(apg1 + (size_t)u * 8) = pk.v;
    }
}

// ---------------- kernel 1: xx = Wx·x as MFMA GEMM, interleaved bf16 out ----------------
__global__ __launch_bounds__(256) void k_xx_mfma(
        const unsigned short* __restrict__ xb, const unsigned short* __restrict__ apx,
        unsigned short* __restrict__ xxb) {
    int bid = blockIdx.x;
    int n = bid / 27, pc = bid % 27;
    int tid = threadIdx.x;
    int w = tid >> 6, lane = tid & 63;
    int ln = lane & 15, kgrp = lane >> 4;
    const bvec8* A = (const bvec8*)apx;
    bvec8 af[4][4];
    #pragma unroll
    for (int s = 0; s < 4; ++s)
        #pragma unroll
        for (int i = 0; i < 4; ++i)
            af[s][i] = A[(s * 16 + w * 4 + i) * 64 + lane];
    fvec4 acc[4][3];
    #pragma unroll
    for (int i = 0; i < 4; ++i)
        #pragma unroll
        for (int jn = 0; jn < 3; ++jn)
            acc[i][jn] = fvec4{0.f, 0.f, 0.f, 0.f};
    #pragma unroll
    for (int s = 0; s < 4; ++s) {
        #pragma unroll
        for (int jn = 0; jn < 3; ++jn) {
            int p = pc * 48 + jn * 16 + ln;
            bvec8 bfr = *(const bvec8*)(xb + ((size_t)(n * 16 + s * 4 + kgrp) * HW + p) * 8);
            #pragma unroll
            for (int i = 0; i < 4; ++i)
                acc[i][jn] = __builtin_amdgcn_mfma_f32_16x16x32_bf16(af[s][i], bfr, acc[i][jn], 0, 0, 0);
        }
    }
    #pragma unroll
    for (int i = 0; i < 4; ++i) {
        int co0 = (w * 4 + i) * 16 + kgrp * 4;
        int icb = co0 >> 3, sub = co0 & 7;
        #pragma unroll
        for (int jn = 0; jn < 3; ++jn) {
            int p = pc * 48 + jn * 16 + ln;
            union { unsigned short us[4]; unsigned long long u; } pk;
            #pragma unroll
            for (int r = 0; r < 4; ++r) pk.us[r] = f2bf(acc[i][jn][r]);
            *(unsigned long long*)(xxb + ((size_t)(n * 32 + icb) * HW + p) * 8 + sub) = pk.u;
        }
    }
}

// ---------------- kernel 2: MFMA grouped 3x3 conv -> qT, kT, vB ----------------
__global__ __launch_bounds__(384) void k_qkv_mfma(
        const unsigned short* __restrict__ xxb, const unsigned short* __restrict__ h0b,
        const unsigned short* __restrict__ apq,
        unsigned short* __restrict__ qT, unsigned short* __restrict__ kT,
        unsigned short* __restrict__ vB) {
    int bid = blockIdx.x;
    int n = bid / 72, rem = bid % 72;
    int g = rem / 9, yt = rem % 9;
    __shared__ bvec8 sm[1824];
    int tid = threadIdx.x;
    for (int u = tid; u < 1824; u += 384) {
        int col = u % 38; int t2 = u / 38;
        int icb = t2 % 8; int rr = t2 / 8;
        int y = yt * 4 - 1 + rr, cx = col - 1;
        bvec8 val = {0, 0, 0, 0, 0, 0, 0, 0};
        if (y >= 0 && y < 36 && cx >= 0 && cx < 36) {
            const unsigned short* src = (icb < 4)
                ? (xxb + ((size_t)(n * 32 + g * 4 + icb) * HW) * 8)
                : (h0b + ((size_t)(n * 32 + g * 4 + icb - 4) * HW) * 8);
            val = *(const bvec8*)(src + (size_t)(y * 36 + cx) * 8);
        }
        int s = rr * 38 + col;
        sm[s * 8 + (icb ^ (s & 7))] = val;
    }
    __syncthreads();
    int lane = tid & 63, w = tid >> 6;
    int mg = w % 3, nh = w / 3;
    int kgrp = lane >> 4;
    int nf0 = nh * 4;
    int sb[5], pl[5];
    #pragma unroll
    for (int jn = 0; jn < 5; ++jn) {
        int p = (nf0 + jn) * 16 + (lane & 15);
        pl[jn] = p;
        sb[jn] = (p / 36) * 38 + (p % 36);
    }
    fvec4 acc[2][5];
    #pragma unroll
    for (int i = 0; i < 2; ++i)
        #pragma unroll
        for (int jn = 0; jn < 5; ++jn)
            acc[i][jn] = fvec4{0.f, 0.f, 0.f, 0.f};
    const bvec8* ap = (const bvec8*)apq + (size_t)g * 6912 + mg * 128 + lane;
    for (int s = 0; s < 18; ++s) {
        int kyx = s >> 1, icb = s & 1;
        int ky = kyx / 3, kx = kyx % 3;
        bvec8 a0 = ap[0], a1 = ap[64];
        ap += 384;
        int soff = ky * 38 + kx;
        int ib = icb * 4 + kgrp;
        #pragma unroll
        for (int jn = 0; jn < 5; ++jn) {
            int slot = sb[jn] + soff;
            bvec8 bfr = sm[slot * 8 + (ib ^ (slot & 7))];
            acc[0][jn] = __builtin_amdgcn_mfma_f32_16x16x32_bf16(a0, bfr, acc[0][jn], 0, 0, 0);
            acc[1][jn] = __builtin_amdgcn_mfma_f32_16x16x32_bf16(a1, bfr, acc[1][jn], 0, 0, 0);
        }
    }
    int ngb = n * 8 + g;
    unsigned short* qTg = qT + (size_t)ngb * 41472;
    unsigned short* kTg = kT + (size_t)ngb * 36992;
    unsigned short* vBg = vB + (size_t)ngb * 37120;
    #pragma unroll
    for (int i = 0; i < 2; ++i) {
        int mf = mg * 2 + i;
        int m0 = mf * 16 + kgrp * 4;
        int conv = m0 >> 5, c0 = m0 & 31;
        #pragma unroll
        for (int jn = 0; jn < 5; ++jn) {
            int gp = yt * 144 + pl[jn];
            int py = gp / 36, px = gp % 36;
            if (conv == 0) {
                union { unsigned short us[4]; unsigned long long u; } pk;
                #pragma unroll
                for (int r = 0; r < 4; ++r) pk.us[r] = f2bf(acc[i][jn][r]);
                *(unsigned long long*)(qTg + (size_t)gp * 32 + c0) = pk.u;
            } else if (py >= 1 && py <= 34 && px >= 1 && px <= 34) {
                int dpix = (py - 1) * 34 + (px - 1);
                if (conv == 1) {
                    union { unsigned short us[4]; unsigned long long u; } pk;
                    #pragma unroll
                    for (int r = 0; r < 4; ++r) pk.us[r] = f2bf(acc[i][jn][r]);
                    *(unsigned long long*)(kTg + (size_t)dpix * 32 + c0) = pk.u;
                } else {
                    #pragma unroll
                    for (int r = 0; r < 4; ++r)
                        vBg[(size_t)(c0 + r) * 1160 + dpix] = f2bf(acc[i][jn][r]);
                }
            }
        }
    }
}

// ---------------- kernel 3: MFMA flash attention, no-max softmax -> ab ----------------
// Logits are analytically bounded (|s| ≲ 12 ≪ 87): p = expf(s) raw, normalize at end.
__global__ __launch_bounds__(256) void k_attn_mfma(
        const unsigned short* __restrict__ qT, const unsigned short* __restrict__ kT,
        const unsigned short* __restrict__ vB, unsigned short* __restrict__ ab) {
    int bid = blockIdx.x;
    int ng = bid / 21, bt = bid % 21;
    int tid = threadIdx.x;
    int w = tid >> 6, l = tid & 63;
    int qblk = bt * 4 + w;
    bool qvalid = qblk < 81;
    int qb = qvalid ? qblk : 80;
    int ln = l & 15, g = l >> 4;
    __shared__ unsigned short sP[4][640];
    const unsigned short* qTg = qT + (size_t)ng * 41472;
    const unsigned short* kTg = kT + (size_t)ng * 36992;
    const unsigned short* vBg = vB + (size_t)ng * 37120;
    bvec8 qf = *(const bvec8*)(qTg + (size_t)(qb * 16 + ln) * 32 + g * 8);
    fvec4 acc0 = {0.f, 0.f, 0.f, 0.f}, acc1 = {0.f, 0.f, 0.f, 0.f};
    fvec4 zero = {0.f, 0.f, 0.f, 0.f};
    float lp = 0.f;
    for (int dt = 0; dt < DDS; dt += 32) {
        int d0 = dt + ln;
        bvec8 kA0 = *(const bvec8*)(kTg + (size_t)min(d0, 1155) * 32 + g * 8);
        bvec8 kA1 = *(const bvec8*)(kTg + (size_t)min(d0 + 16, 1155) * 32 + g * 8);
        bvec8 vA0 = *(const bvec8*)(vBg + (size_t)ln * 1160 + dt + g * 8);
        bvec8 vA1 = *(const bvec8*)(vBg + (size_t)(16 + ln) * 1160 + dt + g * 8);
        fvec4 s0 = __builtin_amdgcn_mfma_f32_16x16x32_bf16(kA0, qf, zero, 0, 0, 0);
        fvec4 s1 = __builtin_amdgcn_mfma_f32_16x16x32_bf16(kA1, qf, zero, 0, 0, 0);
        if (dt + 32 > DDS) {          // tail: only d 1152..1155 valid (g==0, s0)
            if (g > 0) { s0[0] = s0[1] = s0[2] = s0[3] = -1e30f; }
            s1[0] = s1[1] = s1[2] = s1[3] = -1e30f;
        }
        float p[8];
        #pragma unroll
        for (int r = 0; r < 4; ++r) {
            p[r]     = __expf(s0[r]);
            p[4 + r] = __expf(s1[r]);
        }
        lp += ((p[0] + p[1]) + (p[2] + p[3])) + ((p[4] + p[5]) + (p[6] + p[7]));
        union { unsigned int ui[2]; unsigned long long u; } w0, w1;
        w0.ui[0] = cvtpk_bf16(p[0], p[1]);
        w0.ui[1] = cvtpk_bf16(p[2], p[3]);
        w1.ui[0] = cvtpk_bf16(p[4], p[5]);
        w1.ui[1] = cvtpk_bf16(p[6], p[7]);
        *(unsigned long long*)&sP[w][ln * 40 + g * 4]      = w0.u;
        *(unsigned long long*)&sP[w][ln * 40 + 16 + g * 4] = w1.u;
        bvec8 pB = *(bvec8*)&sP[w][ln * 40 + g * 8];
        acc0 = __builtin_amdgcn_mfma_f32_16x16x32_bf16(vA0, pB, acc0, 0, 0, 0);
        acc1 = __builtin_amdgcn_mfma_f32_16x16x32_bf16(vA1, pB, acc1, 0, 0, 0);
    }
    float lt = lp;
    lt += __shfl_xor(lt, 16, 64);
    lt += __shfl_xor(lt, 32, 64);
    float inv = 1.f / lt;
    if (qvalid) {
        int qpos = qblk * 16 + ln;
        unsigned short* ag = ab + (size_t)ng * 41472;
        int sub = (g & 1) * 4;
        union { unsigned short us[4]; unsigned long long u; } pk0, pk1;
        #pragma unroll
        for (int r = 0; r < 4; ++r) {
            pk0.us[r] = f2bf(acc0[r] * inv);
            pk1.us[r] = f2bf(acc1[r] * inv);
        }
        *(unsigned long long*)(ag + ((size_t)(g >> 1) * HW + qpos) * 8 + sub)       = pk0.u;
        *(unsigned long long*)(ag + ((size_t)(2 + (g >> 1)) * HW + qpos) * 8 + sub) = pk1.u;
    }
}

// ---------------- kernel 4: MFMA gates + LSTM combine ----------------
__global__ __launch_bounds__(256) void k_gates_mfma(
        const unsigned short* __restrict__ xxb, const unsigned short* __restrict__ h0b,
        const float* __restrict__ c0, const unsigned short* __restrict__ ab,
        const unsigned short* __restrict__ apg2, const unsigned short* __restrict__ apg1,
        const float* __restrict__ bi, const float* __restrict__ bf_,
        const float* __restrict__ bg, const float* __restrict__ bo,
        float* __restrict__ out) {
    int bid = blockIdx.x;
    int n = bid / 72, rem = bid % 72;
    int g = rem / 9, yt = rem % 9;
    __shared__ bvec8 smx[1824];
    __shared__ bvec8 sma[576];
    int tid = threadIdx.x;
    for (int u = tid; u < 1824; u += 256) {
        int col = u % 38; int t2 = u / 38;
        int icb = t2 % 8; int rr = t2 / 8;
        int y = yt * 4 - 1 + rr, cx = col - 1;
        bvec8 val = {0, 0, 0, 0, 0, 0, 0, 0};
        if (y >= 0 && y < 36 && cx >= 0 && cx < 36) {
            const unsigned short* src = (icb < 4)
                ? (xxb + ((size_t)(n * 32 + g * 4 + icb) * HW) * 8)
                : (h0b + ((size_t)(n * 32 + g * 4 + icb - 4) * HW) * 8);
            val = *(const bvec8*)(src + (size_t)(y * 36 + cx) * 8);
        }
        int s = rr * 38 + col;
        smx[s * 8 + (icb ^ (s & 7))] = val;
    }
    int ngb = n * 8 + g;
    for (int u = tid; u < 576; u += 256) {
        int p = u % 144, cb = u / 144;
        int gp = yt * 144 + p;
        bvec8 val = *(const bvec8*)(ab + ((size_t)(ngb * 4 + cb) * HW + gp) * 8);
        sma[p * 4 + (cb ^ (p & 3))] = val;
    }
    __syncthreads();
    int lane = tid & 63, w = tid >> 6;
    int b = w & 1, nh = w >> 1;
    int kgrp = lane >> 4, nf0 = nh * 4;
    int sb[5], pl[5];
    #pragma unroll
    for (int jn = 0; jn < 5; ++jn) {
        int p = (nf0 + jn) * 16 + (lane & 15);
        pl[jn] = p;
        sb[jn] = (p / 36) * 38 + (p % 36);
    }
    fvec4 acc[4][5];
    #pragma unroll
    for (int i = 0; i < 4; ++i)
        #pragma unroll
        for (int jn = 0; jn < 5; ++jn)
            acc[i][jn] = fvec4{0.f, 0.f, 0.f, 0.f};
    const bvec8* ap = (const bvec8*)apg2 + ((size_t)g * 144 + b) * 64 + lane;
    for (int s = 0; s < 18; ++s) {
        int kyx = s >> 1, icb = s & 1;
        int ky = kyx / 3, kx = kyx % 3;
        bvec8 a0 = ap[0], a1 = ap[128], a2 = ap[256], a3 = ap[384];
        ap += 512;
        int soff = ky * 38 + kx;
        int ib = icb * 4 + kgrp;
        #pragma unroll
        for (int jn = 0; jn < 5; ++jn) {
            int slot = sb[jn] + soff;
            bvec8 bfr = smx[slot * 8 + (ib ^ (slot & 7))];
            acc[0][jn] = __builtin_amdgcn_mfma_f32_16x16x32_bf16(a0, bfr, acc[0][jn], 0, 0, 0);
            acc[1][jn] = __builtin_amdgcn_mfma_f32_16x16x32_bf16(a1, bfr, acc[1][jn], 0, 0, 0);
            acc[2][jn] = __builtin_amdgcn_mfma_f32_16x16x32_bf16(a2, bfr, acc[2][jn], 0, 0, 0);
            acc[3][jn] = __builtin_amdgcn_mfma_f32_16x16x32_bf16(a3, bfr, acc[3][jn], 0, 0, 0);
        }
    }
    {
        const bvec8* ap1 = (const bvec8*)apg1 + ((size_t)g * 8 + b) * 64 + lane;
        bvec8 a0 = ap1[0], a1 = ap1[128], a2 = ap1[256], a3 = ap1[384];
        #pragma unroll
        for (int jn = 0; jn < 5; ++jn) {
            int p = pl[jn];
            bvec8 bfr = sma[p * 4 + (kgrp ^ (p & 3))];
            acc[0][jn] = __builtin_amdgcn_mfma_f32_16x16x32_bf16(a0, bfr, acc[0][jn], 0, 0, 0);
            acc[1][jn] = __builtin_amdgcn_mfma_f32_16x16x32_bf16(a1, bfr, acc[1][jn], 0, 0, 0);
            acc[2][jn] = __builtin_amdgcn_mfma_f32_16x16x32_bf16(a2, bfr, acc[2][jn], 0, 0, 0);
            acc[3][jn] = __builtin_amdgcn_mfma_f32_16x16x32_bf16(a3, bfr, acc[3][jn], 0, 0, 0);
        }
    }
    #pragma unroll
    for (int jn = 0; jn < 5; ++jn) {
        int gp = yt * 144 + pl[jn];
        #pragma unroll
        for (int r = 0; r < 4; ++r) {
            int cl = b * 16 + kgrp * 4 + r;
            int co = g * 32 + cl;
            float ip   = acc[0][jn][r] + bi[co];
            float fp   = acc[1][jn][r] + bf_[co];
            float gpre = acc[2][jn][r] + bg[co];
            float op   = acc[3][jn][r] + bo[co];
            float iv = sigmoidf_(ip), fv = sigmoidf_(fp);
            float gv = tanhf_(gpre), ov = sigmoidf_(op);
            float cv = fmaf(fv, c0[(size_t)(n * CC + co) * HW + gp], iv * gv);
            out[(size_t)(n * CC + co) * HW + gp] = ov * tanhf_(cv);
        }
    }
}

extern "C" void kernel_launch(void* const* d_in, const int* in_sizes, int n_in,
                              void* d_out, int out_size, void* d_ws, size_t ws_size,
                              hipStream_t stream) {
    const float* x   = (const float*)d_in[0];
    const float* h0  = (const float*)d_in[1];
    const float* c0  = (const float*)d_in[2];
    const float* Wx  = (const float*)d_in[3];
    const float* Wq  = (const float*)d_in[4];
    const float* Wk  = (const float*)d_in[5];
    const float* Wv  = (const float*)d_in[6];
    const float* Wi1 = (const float*)d_in[7];
    const float* Wi2 = (const float*)d_in[8];
    const float* bi  = (const float*)d_in[9];
    const float* Wf1 = (const float*)d_in[10];
    const float* Wf2 = (const float*)d_in[11];
    const float* bf  = (const float*)d_in[12];
    const float* Wg1 = (const float*)d_in[13];
    const float* Wg2 = (const float*)d_in[14];
    const float* bg  = (const float*)d_in[15];
    const float* Wo1 = (const float*)d_in[16];
    const float* Wo2 = (const float*)d_in[17];
    const float* bo  = (const float*)d_in[18];
    const float* tau = (const float*)d_in[19];

    unsigned short* ws  = (unsigned short*)d_ws;
    unsigned short* xb   = ws;                   // 1,327,104
    unsigned short* h0b  = xb   + 1327104;       // 2,654,208
    unsigned short* xxb  = h0b  + 2654208;       // 2,654,208
    unsigned short* ab   = xxb  + 2654208;       // 2,654,208
    unsigned short* qT   = ab   + 2654208;       // 2,654,208
    unsigned short* kT   = qT   + 2654208;       // 2,367,488
    unsigned short* vB   = kT   + 2367488;       // 2,375,744
    unsigned short* apx  = vB   + 2375744;       // 32,768
    unsigned short* apq  = apx  + 32768;         // 442,368
    unsigned short* apg2 = apq  + 442368;        // 589,824
    unsigned short* apg1 = apg2 + 589824;        // 32,768
    float* out = (float*)d_out;

    hipLaunchKernelGGL(k_prep, dim3(2480), dim3(256), 0, stream,
                       x, h0, Wx, Wq, Wk, Wv, tau,
                       Wi2, Wf2, Wg2, Wo2, Wi1, Wf1, Wg1, Wo1,
                       xb, h0b, apx, apq, apg2, apg1);
    hipLaunchKernelGGL(k_xx_mfma,   dim3(216),  dim3(256), 0, stream, xb, apx, xxb);
    hipLaunchKernelGGL(k_qkv_mfma,  dim3(576),  dim3(384), 0, stream, xxb, h0b, apq, qT, kT, vB);
    hipLaunchKernelGGL(k_attn_mfma, dim3(1344), dim3(256), 0, stream, qT, kT, vB, ab);
    hipLaunchKernelGGL(k_gates_mfma,dim3(576),  dim3(256), 0, stream, xxb, h0b, c0, ab,
                       apg2, apg1, bi, bf, bg, bo, out);
}

// Round 6
// 127.437 us; speedup vs baseline: 17.5842x; 1.0197x over previous
//
#include <hip/hip_runtime.h>
#include <math.h>

#define NN  8
#define CIN 128
#define HW  1296
#define CC  256
#define DDS 1156

typedef __attribute__((ext_vector_type(8))) short bvec8;
typedef __attribute__((ext_vector_type(4))) float fvec4;

__device__ __forceinline__ float sigmoidf_(float x) {
    return 1.f / (1.f + __expf(-x));
}
__device__ __forceinline__ float tanhf_(float x) {
    float xa = fminf(fmaxf(x, -15.f), 15.f);
    float e = __expf(2.f * xa);
    return (e - 1.f) / (e + 1.f);
}
__device__ __forceinline__ unsigned short f2bf(float f) {
    unsigned int u = __float_as_uint(f);
    u = (u + 0x7FFFu + ((u >> 16) & 1u)) >> 16;
    return (unsigned short)u;
}
__device__ __forceinline__ unsigned int cvtpk_bf16(float a, float b) {
    unsigned int r;
    asm("v_cvt_pk_bf16_f32 %0, %1, %2" : "=v"(r) : "v"(a), "v"(b));
    return r;   // lo16 = bf16(a), hi16 = bf16(b), RTNE
}
__device__ __forceinline__ float exp2a(float x) {   // 2^x, single v_exp_f32
    float r;
    asm("v_exp_f32 %0, %1" : "=v"(r) : "v"(x));
    return r;
}

// ---------------- kernel 0: prep ----------------
// blocks 0..383: LDS-transpose x/h0 -> interleaved bf16 (xb/h0b)
// blocks 384..919: pack weights (apq has tau*log2e folded into Wq)
__global__ __launch_bounds__(256) void k_prep(
        const float* __restrict__ x, const float* __restrict__ h0,
        const float* __restrict__ Wx,
        const float* __restrict__ Wq, const float* __restrict__ Wk,
        const float* __restrict__ Wv, const float* __restrict__ tau,
        const float* __restrict__ Wi2, const float* __restrict__ Wf2,
        const float* __restrict__ Wg2, const float* __restrict__ Wo2,
        const float* __restrict__ Wi1, const float* __restrict__ Wf1,
        const float* __restrict__ Wg1, const float* __restrict__ Wo1,
        unsigned short* __restrict__ xb, unsigned short* __restrict__ h0b,
        unsigned short* __restrict__ apx, unsigned short* __restrict__ apq,
        unsigned short* __restrict__ apg2, unsigned short* __restrict__ apg1) {
    __shared__ float tr[10400];          // 8 ch x stride 1300 (bank-clean)
    int bid = blockIdx.x;
    int tid = threadIdx.x;
    if (bid < 384) {
        int n = bid / 48, cb = bid % 48;
        const float* src = (cb < 16) ? x  + (size_t)(n * CIN + cb * 8) * HW
                                     : h0 + (size_t)(n * CC + (cb - 16) * 8) * HW;
        unsigned short* dst = (cb < 16) ? xb  + ((size_t)(n * 16 + cb) * HW) * 8
                                        : h0b + ((size_t)(n * 32 + (cb - 16)) * HW) * 8;
        #pragma unroll
        for (int c = 0; c < 8; ++c)
            for (int p4 = tid; p4 < 324; p4 += 256) {
                float4 v = ((const float4*)(src + (size_t)c * HW))[p4];
                *(float4*)&tr[c * 1300 + p4 * 4] = v;
            }
        __syncthreads();
        for (int p = tid; p < 1296; p += 256) {
            union { unsigned short us[8]; bvec8 v; } pk;
            #pragma unroll
            for (int c = 0; c < 8; ++c) pk.us[c] = f2bf(tr[c * 1300 + p]);
            *(bvec8*)(dst + (size_t)p * 8) = pk.v;
        }
        return;
    }
    int t = (bid - 384) * 256 + tid;
    union { unsigned short us[8]; bvec8 v; } pk;
    if (t < 55296) {                        // apq (Wq scaled by tau*log2e)
        int u = t;
        int lane = u & 63;
        int t2 = u >> 6;
        int mf = t2 % 6, t3 = t2 / 6;
        int s = t3 % 18, g = t3 / 18;
        int kyx = s >> 1, icb = s & 1;
        int ky = kyx / 3, kx = kyx % 3;
        int m = mf * 16 + (lane & 15);
        int conv = m >> 5, cl = m & 31, co = g * 32 + cl;
        int ic0 = icb * 32 + (lane >> 4) * 8;
        const float* W = (conv == 0) ? Wq : (conv == 1 ? Wk : Wv);
        float scale = (conv == 0) ? tau[g] * 1.4426950408889634f : 1.f;
        #pragma unroll
        for (int j = 0; j < 8; ++j)
            pk.us[j] = f2bf(W[((co * 64 + ic0 + j) * 3 + ky) * 3 + kx] * scale);
        *(bvec8*)(apq + (size_t)u * 8) = pk.v;
    } else if (t < 59392) {                 // apx
        int u = t - 55296;
        int lane = u & 63;
        int t2 = u >> 6;
        int mf = t2 % 16, s = t2 / 16;
        int co = mf * 16 + (lane & 15);
        int k0 = s * 32 + (lane >> 4) * 8;
        #pragma unroll
        for (int j = 0; j < 8; ++j)
            pk.us[j] = f2bf(Wx[co * CIN + k0 + j]);
        *(bvec8*)(apx + (size_t)u * 8) = pk.v;
    } else if (t < 133120) {                // apg2
        int u = t - 59392;
        int lane = u & 63;
        int t2 = u >> 6;
        int mf = t2 % 8, t3 = t2 / 8;
        int s = t3 % 18, g = t3 / 18;
        int kyx = s >> 1, icb = s & 1;
        int ky = kyx / 3, kx = kyx % 3;
        int m = mf * 16 + (lane & 15);
        int gate = m >> 5, cl = m & 31, co = g * 32 + cl;
        int ic0 = icb * 32 + (lane >> 4) * 8;
        const float* W = (gate == 0) ? Wi2 : (gate == 1 ? Wf2 : (gate == 2 ? Wg2 : Wo2));
        #pragma unroll
        for (int j = 0; j < 8; ++j)
            pk.us[j] = f2bf(W[((co * 64 + ic0 + j) * 3 + ky) * 3 + kx]);
        *(bvec8*)(apg2 + (size_t)u * 8) = pk.v;
    } else if (t < 137216) {                // apg1
        int u = t - 133120;
        int lane = u & 63;
        int t2 = u >> 6;
        int mf = t2 % 8, g = t2 / 8;
        int m = mf * 16 + (lane & 15);
        int gate = m >> 5, cl = m & 31, co = g * 32 + cl;
        int k0 = (lane >> 4) * 8;
        const float* W = (gate == 0) ? Wi1 : (gate == 1 ? Wf1 : (gate == 2 ? Wg1 : Wo1));
        #pragma unroll
        for (int j = 0; j < 8; ++j)
            pk.us[j] = f2bf(W[co * 32 + k0 + j]);
        *(bvec8*)(apg1 + (size_t)u * 8) = pk.v;
    }
}

// ---------------- kernel 1: xx = Wx·x as MFMA GEMM, interleaved bf16 out ----------------
__global__ __launch_bounds__(256) void k_xx_mfma(
        const unsigned short* __restrict__ xb, const unsigned short* __restrict__ apx,
        unsigned short* __restrict__ xxb) {
    int bid = blockIdx.x;
    int n = bid / 27, pc = bid % 27;
    int tid = threadIdx.x;
    int w = tid >> 6, lane = tid & 63;
    int ln = lane & 15, kgrp = lane >> 4;
    const bvec8* A = (const bvec8*)apx;
    bvec8 af[4][4];
    #pragma unroll
    for (int s = 0; s < 4; ++s)
        #pragma unroll
        for (int i = 0; i < 4; ++i)
            af[s][i] = A[(s * 16 + w * 4 + i) * 64 + lane];
    fvec4 acc[4][3];
    #pragma unroll
    for (int i = 0; i < 4; ++i)
        #pragma unroll
        for (int jn = 0; jn < 3; ++jn)
            acc[i][jn] = fvec4{0.f, 0.f, 0.f, 0.f};
    #pragma unroll
    for (int s = 0; s < 4; ++s) {
        #pragma unroll
        for (int jn = 0; jn < 3; ++jn) {
            int p = pc * 48 + jn * 16 + ln;
            bvec8 bfr = *(const bvec8*)(xb + ((size_t)(n * 16 + s * 4 + kgrp) * HW + p) * 8);
            #pragma unroll
            for (int i = 0; i < 4; ++i)
                acc[i][jn] = __builtin_amdgcn_mfma_f32_16x16x32_bf16(af[s][i], bfr, acc[i][jn], 0, 0, 0);
        }
    }
    #pragma unroll
    for (int i = 0; i < 4; ++i) {
        int co0 = (w * 4 + i) * 16 + kgrp * 4;
        int icb = co0 >> 3, sub = co0 & 7;
        #pragma unroll
        for (int jn = 0; jn < 3; ++jn) {
            int p = pc * 48 + jn * 16 + ln;
            union { unsigned short us[4]; unsigned long long u; } pk;
            #pragma unroll
            for (int r = 0; r < 4; ++r) pk.us[r] = f2bf(acc[i][jn][r]);
            *(unsigned long long*)(xxb + ((size_t)(n * 32 + icb) * HW + p) * 8 + sub) = pk.u;
        }
    }
}

// ---------------- kernel 2: MFMA grouped 3x3 conv -> qT, kT, vB ----------------
__global__ __launch_bounds__(384) void k_qkv_mfma(
        const unsigned short* __restrict__ xxb, const unsigned short* __restrict__ h0b,
        const unsigned short* __restrict__ apq,
        unsigned short* __restrict__ qT, unsigned short* __restrict__ kT,
        unsigned short* __restrict__ vB) {
    int bid = blockIdx.x;
    int n = bid / 72, rem = bid % 72;
    int g = rem / 9, yt = rem % 9;
    __shared__ bvec8 sm[1824];
    int tid = threadIdx.x;
    for (int u = tid; u < 1824; u += 384) {
        int col = u % 38; int t2 = u / 38;
        int icb = t2 % 8; int rr = t2 / 8;
        int y = yt * 4 - 1 + rr, cx = col - 1;
        bvec8 val = {0, 0, 0, 0, 0, 0, 0, 0};
        if (y >= 0 && y < 36 && cx >= 0 && cx < 36) {
            const unsigned short* src = (icb < 4)
                ? (xxb + ((size_t)(n * 32 + g * 4 + icb) * HW) * 8)
                : (h0b + ((size_t)(n * 32 + g * 4 + icb - 4) * HW) * 8);
            val = *(const bvec8*)(src + (size_t)(y * 36 + cx) * 8);
        }
        int s = rr * 38 + col;
        sm[s * 8 + (icb ^ (s & 7))] = val;
    }
    __syncthreads();
    int lane = tid & 63, w = tid >> 6;
    int mg = w % 3, nh = w / 3;
    int kgrp = lane >> 4;
    int nf0 = nh * 4;
    int sb[5], pl[5];
    #pragma unroll
    for (int jn = 0; jn < 5; ++jn) {
        int p = (nf0 + jn) * 16 + (lane & 15);
        pl[jn] = p;
        sb[jn] = (p / 36) * 38 + (p % 36);
    }
    fvec4 acc[2][5];
    #pragma unroll
    for (int i = 0; i < 2; ++i)
        #pragma unroll
        for (int jn = 0; jn < 5; ++jn)
            acc[i][jn] = fvec4{0.f, 0.f, 0.f, 0.f};
    const bvec8* ap = (const bvec8*)apq + (size_t)g * 6912 + mg * 128 + lane;
    for (int s = 0; s < 18; ++s) {
        int kyx = s >> 1, icb = s & 1;
        int ky = kyx / 3, kx = kyx % 3;
        bvec8 a0 = ap[0], a1 = ap[64];
        ap += 384;
        int soff = ky * 38 + kx;
        int ib = icb * 4 + kgrp;
        #pragma unroll
        for (int jn = 0; jn < 5; ++jn) {
            int slot = sb[jn] + soff;
            bvec8 bfr = sm[slot * 8 + (ib ^ (slot & 7))];
            acc[0][jn] = __builtin_amdgcn_mfma_f32_16x16x32_bf16(a0, bfr, acc[0][jn], 0, 0, 0);
            acc[1][jn] = __builtin_amdgcn_mfma_f32_16x16x32_bf16(a1, bfr, acc[1][jn], 0, 0, 0);
        }
    }
    int ngb = n * 8 + g;
    unsigned short* qTg = qT + (size_t)ngb * 41472;
    unsigned short* kTg = kT + (size_t)ngb * 36992;
    unsigned short* vBg = vB + (size_t)ngb * 37120;
    #pragma unroll
    for (int i = 0; i < 2; ++i) {
        int mf = mg * 2 + i;
        int m0 = mf * 16 + kgrp * 4;
        int conv = m0 >> 5, c0 = m0 & 31;
        #pragma unroll
        for (int jn = 0; jn < 5; ++jn) {
            int gp = yt * 144 + pl[jn];
            int py = gp / 36, px = gp % 36;
            if (conv == 0) {
                union { unsigned short us[4]; unsigned long long u; } pk;
                #pragma unroll
                for (int r = 0; r < 4; ++r) pk.us[r] = f2bf(acc[i][jn][r]);
                *(unsigned long long*)(qTg + (size_t)gp * 32 + c0) = pk.u;
            } else if (py >= 1 && py <= 34 && px >= 1 && px <= 34) {
                int dpix = (py - 1) * 34 + (px - 1);
                if (conv == 1) {
                    union { unsigned short us[4]; unsigned long long u; } pk;
                    #pragma unroll
                    for (int r = 0; r < 4; ++r) pk.us[r] = f2bf(acc[i][jn][r]);
                    *(unsigned long long*)(kTg + (size_t)dpix * 32 + c0) = pk.u;
                } else {
                    #pragma unroll
                    for (int r = 0; r < 4; ++r)
                        vBg[(size_t)(c0 + r) * 1160 + dpix] = f2bf(acc[i][jn][r]);
                }
            }
        }
    }
}

// ---------------- kernel 3: MFMA flash attention, pipelined, no-max softmax ----------------
// Wq carries tau*log2e, so p = 2^s via bare v_exp_f32. 36 clean 32-key tiles + masked 4-key tail.
__global__ __launch_bounds__(256) void k_attn_mfma(
        const unsigned short* __restrict__ qT, const unsigned short* __restrict__ kT,
        const unsigned short* __restrict__ vB, unsigned short* __restrict__ ab) {
    int bid = blockIdx.x;
    int ng = bid / 21, bt = bid % 21;
    int tid = threadIdx.x;
    int w = tid >> 6, l = tid & 63;
    int qblk = bt * 4 + w;
    bool qvalid = qblk < 81;
    int qb = qvalid ? qblk : 80;
    int ln = l & 15, g = l >> 4;
    __shared__ unsigned short sP[4][640];
    const unsigned short* qTg = qT + (size_t)ng * 41472;
    const unsigned short* kTg = kT + (size_t)ng * 36992;
    const unsigned short* vBg = vB + (size_t)ng * 37120;
    bvec8 qf = *(const bvec8*)(qTg + (size_t)(qb * 16 + ln) * 32 + g * 8);
    const unsigned short* kp = kTg + ln * 32 + g * 8;           // + t*1024 (+512 for hi 16 keys)
    const unsigned short* vp = vBg + (size_t)ln * 1160 + g * 8; // + t*32  (+18560 for rows 16..31)
    unsigned short* sw0 = &sP[w][ln * 40 + g * 4];
    unsigned short* sw1 = &sP[w][ln * 40 + 16 + g * 4];
    const unsigned short* sr = &sP[w][ln * 40 + g * 8];
    fvec4 acc0 = {0.f, 0.f, 0.f, 0.f}, acc1 = {0.f, 0.f, 0.f, 0.f};
    fvec4 zero = {0.f, 0.f, 0.f, 0.f};
    float lp = 0.f;
    bvec8 ka0 = *(const bvec8*)(kp);
    bvec8 ka1 = *(const bvec8*)(kp + 512);
    bvec8 va0 = *(const bvec8*)(vp);
    bvec8 va1 = *(const bvec8*)(vp + 18560);
    #pragma unroll 2
    for (int t = 0; t < 36; ++t) {
        int tn = (t < 35) ? t + 1 : 35;
        bvec8 nk0 = *(const bvec8*)(kp + tn * 1024);
        bvec8 nk1 = *(const bvec8*)(kp + tn * 1024 + 512);
        bvec8 nv0 = *(const bvec8*)(vp + tn * 32);
        bvec8 nv1 = *(const bvec8*)(vp + tn * 32 + 18560);
        fvec4 s0 = __builtin_amdgcn_mfma_f32_16x16x32_bf16(ka0, qf, zero, 0, 0, 0);
        fvec4 s1 = __builtin_amdgcn_mfma_f32_16x16x32_bf16(ka1, qf, zero, 0, 0, 0);
        float p[8];
        #pragma unroll
        for (int r = 0; r < 4; ++r) {
            p[r]     = exp2a(s0[r]);
            p[4 + r] = exp2a(s1[r]);
        }
        lp += ((p[0] + p[1]) + (p[2] + p[3])) + ((p[4] + p[5]) + (p[6] + p[7]));
        union { unsigned int ui[2]; unsigned long long u; } w0, w1;
        w0.ui[0] = cvtpk_bf16(p[0], p[1]);
        w0.ui[1] = cvtpk_bf16(p[2], p[3]);
        w1.ui[0] = cvtpk_bf16(p[4], p[5]);
        w1.ui[1] = cvtpk_bf16(p[6], p[7]);
        *(unsigned long long*)sw0 = w0.u;
        *(unsigned long long*)sw1 = w1.u;
        bvec8 pB = *(const bvec8*)sr;
        acc0 = __builtin_amdgcn_mfma_f32_16x16x32_bf16(va0, pB, acc0, 0, 0, 0);
        acc1 = __builtin_amdgcn_mfma_f32_16x16x32_bf16(va1, pB, acc1, 0, 0, 0);
        ka0 = nk0; ka1 = nk1; va0 = nv0; va1 = nv1;
    }
    {   // tail: keys 1152..1155 (valid only for g==0, rows 0..3 of s0)
        bvec8 tk = *(const bvec8*)(kTg + (size_t)min(1152 + ln, 1155) * 32 + g * 8);
        fvec4 s0 = __builtin_amdgcn_mfma_f32_16x16x32_bf16(tk, qf, zero, 0, 0, 0);
        float p[4];
        #pragma unroll
        for (int r = 0; r < 4; ++r)
            p[r] = (g == 0) ? exp2a(s0[r]) : 0.f;
        lp += (p[0] + p[1]) + (p[2] + p[3]);
        union { unsigned int ui[2]; unsigned long long u; } w0;
        w0.ui[0] = cvtpk_bf16(p[0], p[1]);
        w0.ui[1] = cvtpk_bf16(p[2], p[3]);
        *(unsigned long long*)sw0 = w0.u;
        *(unsigned long long*)sw1 = 0ull;
        bvec8 pB = *(const bvec8*)sr;
        bvec8 tv0 = *(const bvec8*)(vp + 36 * 32);
        bvec8 tv1 = *(const bvec8*)(vp + 36 * 32 + 18560);
        acc0 = __builtin_amdgcn_mfma_f32_16x16x32_bf16(tv0, pB, acc0, 0, 0, 0);
        acc1 = __builtin_amdgcn_mfma_f32_16x16x32_bf16(tv1, pB, acc1, 0, 0, 0);
    }
    float lt = lp;
    lt += __shfl_xor(lt, 16, 64);
    lt += __shfl_xor(lt, 32, 64);
    float inv = 1.f / lt;
    if (qvalid) {
        int qpos = qblk * 16 + ln;
        unsigned short* ag = ab + (size_t)ng * 41472;
        int sub = (g & 1) * 4;
        union { unsigned short us[4]; unsigned long long u; } pk0, pk1;
        #pragma unroll
        for (int r = 0; r < 4; ++r) {
            pk0.us[r] = f2bf(acc0[r] * inv);
            pk1.us[r] = f2bf(acc1[r] * inv);
        }
        *(unsigned long long*)(ag + ((size_t)(g >> 1) * HW + qpos) * 8 + sub)       = pk0.u;
        *(unsigned long long*)(ag + ((size_t)(2 + (g >> 1)) * HW + qpos) * 8 + sub) = pk1.u;
    }
}

// ---------------- kernel 4: MFMA gates + LSTM combine ----------------
__global__ __launch_bounds__(256) void k_gates_mfma(
        const unsigned short* __restrict__ xxb, const unsigned short* __restrict__ h0b,
        const float* __restrict__ c0, const unsigned short* __restrict__ ab,
        const unsigned short* __restrict__ apg2, const unsigned short* __restrict__ apg1,
        const float* __restrict__ bi, const float* __restrict__ bf_,
        const float* __restrict__ bg, const float* __restrict__ bo,
        float* __restrict__ out) {
    int bid = blockIdx.x;
    int n = bid / 72, rem = bid % 72;
    int g = rem / 9, yt = rem % 9;
    __shared__ bvec8 smx[1824];
    __shared__ bvec8 sma[576];
    int tid = threadIdx.x;
    for (int u = tid; u < 1824; u += 256) {
        int col = u % 38; int t2 = u / 38;
        int icb = t2 % 8; int rr = t2 / 8;
        int y = yt * 4 - 1 + rr, cx = col - 1;
        bvec8 val = {0, 0, 0, 0, 0, 0, 0, 0};
        if (y >= 0 && y < 36 && cx >= 0 && cx < 36) {
            const unsigned short* src = (icb < 4)
                ? (xxb + ((size_t)(n * 32 + g * 4 + icb) * HW) * 8)
                : (h0b + ((size_t)(n * 32 + g * 4 + icb - 4) * HW) * 8);
            val = *(const bvec8*)(src + (size_t)(y * 36 + cx) * 8);
        }
        int s = rr * 38 + col;
        smx[s * 8 + (icb ^ (s & 7))] = val;
    }
    int ngb = n * 8 + g;
    for (int u = tid; u < 576; u += 256) {
        int p = u % 144, cb = u / 144;
        int gp = yt * 144 + p;
        bvec8 val = *(const bvec8*)(ab + ((size_t)(ngb * 4 + cb) * HW + gp) * 8);
        sma[p * 4 + (cb ^ (p & 3))] = val;
    }
    __syncthreads();
    int lane = tid & 63, w = tid >> 6;
    int b = w & 1, nh = w >> 1;
    int kgrp = lane >> 4, nf0 = nh * 4;
    int sb[5], pl[5];
    #pragma unroll
    for (int jn = 0; jn < 5; ++jn) {
        int p = (nf0 + jn) * 16 + (lane & 15);
        pl[jn] = p;
        sb[jn] = (p / 36) * 38 + (p % 36);
    }
    fvec4 acc[4][5];
    #pragma unroll
    for (int i = 0; i < 4; ++i)
        #pragma unroll
        for (int jn = 0; jn < 5; ++jn)
            acc[i][jn] = fvec4{0.f, 0.f, 0.f, 0.f};
    const bvec8* ap = (const bvec8*)apg2 + ((size_t)g * 144 + b) * 64 + lane;
    for (int s = 0; s < 18; ++s) {
        int kyx = s >> 1, icb = s & 1;
        int ky = kyx / 3, kx = kyx % 3;
        bvec8 a0 = ap[0], a1 = ap[128], a2 = ap[256], a3 = ap[384];
        ap += 512;
        int soff = ky * 38 + kx;
        int ib = icb * 4 + kgrp;
        #pragma unroll
        for (int jn = 0; jn < 5; ++jn) {
            int slot = sb[jn] + soff;
            bvec8 bfr = smx[slot * 8 + (ib ^ (slot & 7))];
            acc[0][jn] = __builtin_amdgcn_mfma_f32_16x16x32_bf16(a0, bfr, acc[0][jn], 0, 0, 0);
            acc[1][jn] = __builtin_amdgcn_mfma_f32_16x16x32_bf16(a1, bfr, acc[1][jn], 0, 0, 0);
            acc[2][jn] = __builtin_amdgcn_mfma_f32_16x16x32_bf16(a2, bfr, acc[2][jn], 0, 0, 0);
            acc[3][jn] = __builtin_amdgcn_mfma_f32_16x16x32_bf16(a3, bfr, acc[3][jn], 0, 0, 0);
        }
    }
    {
        const bvec8* ap1 = (const bvec8*)apg1 + ((size_t)g * 8 + b) * 64 + lane;
        bvec8 a0 = ap1[0], a1 = ap1[128], a2 = ap1[256], a3 = ap1[384];
        #pragma unroll
        for (int jn = 0; jn < 5; ++jn) {
            int p = pl[jn];
            bvec8 bfr = sma[p * 4 + (kgrp ^ (p & 3))];
            acc[0][jn] = __builtin_amdgcn_mfma_f32_16x16x32_bf16(a0, bfr, acc[0][jn], 0, 0, 0);
            acc[1][jn] = __builtin_amdgcn_mfma_f32_16x16x32_bf16(a1, bfr, acc[1][jn], 0, 0, 0);
            acc[2][jn] = __builtin_amdgcn_mfma_f32_16x16x32_bf16(a2, bfr, acc[2][jn], 0, 0, 0);
            acc[3][jn] = __builtin_amdgcn_mfma_f32_16x16x32_bf16(a3, bfr, acc[3][jn], 0, 0, 0);
        }
    }
    #pragma unroll
    for (int jn = 0; jn < 5; ++jn) {
        int gp = yt * 144 + pl[jn];
        #pragma unroll
        for (int r = 0; r < 4; ++r) {
            int cl = b * 16 + kgrp * 4 + r;
            int co = g * 32 + cl;
            float ip   = acc[0][jn][r] + bi[co];
            float fp   = acc[1][jn][r] + bf_[co];
            float gpre = acc[2][jn][r] + bg[co];
            float op   = acc[3][jn][r] + bo[co];
            float iv = sigmoidf_(ip), fv = sigmoidf_(fp);
            float gv = tanhf_(gpre), ov = sigmoidf_(op);
            float cv = fmaf(fv, c0[(size_t)(n * CC + co) * HW + gp], iv * gv);
            out[(size_t)(n * CC + co) * HW + gp] = ov * tanhf_(cv);
        }
    }
}

extern "C" void kernel_launch(void* const* d_in, const int* in_sizes, int n_in,
                              void* d_out, int out_size, void* d_ws, size_t ws_size,
                              hipStream_t stream) {
    const float* x   = (const float*)d_in[0];
    const float* h0  = (const float*)d_in[1];
    const float* c0  = (const float*)d_in[2];
    const float* Wx  = (const float*)d_in[3];
    const float* Wq  = (const float*)d_in[4];
    const float* Wk  = (const float*)d_in[5];
    const float* Wv  = (const float*)d_in[6];
    const float* Wi1 = (const float*)d_in[7];
    const float* Wi2 = (const float*)d_in[8];
    const float* bi  = (const float*)d_in[9];
    const float* Wf1 = (const float*)d_in[10];
    const float* Wf2 = (const float*)d_in[11];
    const float* bf  = (const float*)d_in[12];
    const float* Wg1 = (const float*)d_in[13];
    const float* Wg2 = (const float*)d_in[14];
    const float* bg  = (const float*)d_in[15];
    const float* Wo1 = (const float*)d_in[16];
    const float* Wo2 = (const float*)d_in[17];
    const float* bo  = (const float*)d_in[18];
    const float* tau = (const float*)d_in[19];

    unsigned short* ws  = (unsigned short*)d_ws;
    unsigned short* xb   = ws;                   // 1,327,104
    unsigned short* h0b  = xb   + 1327104;       // 2,654,208
    unsigned short* xxb  = h0b  + 2654208;       // 2,654,208
    unsigned short* ab   = xxb  + 2654208;       // 2,654,208
    unsigned short* qT   = ab   + 2654208;       // 2,654,208
    unsigned short* kT   = qT   + 2654208;       // 2,367,488
    unsigned short* vB   = kT   + 2367488;       // 2,375,744
    unsigned short* apx  = vB   + 2375744;       // 32,768
    unsigned short* apq  = apx  + 32768;         // 442,368
    unsigned short* apg2 = apq  + 442368;        // 589,824
    unsigned short* apg1 = apg2 + 589824;        // 32,768
    float* out = (float*)d_out;

    hipLaunchKernelGGL(k_prep, dim3(920), dim3(256), 0, stream,
                       x, h0, Wx, Wq, Wk, Wv, tau,
                       Wi2, Wf2, Wg2, Wo2, Wi1, Wf1, Wg1, Wo1,
                       xb, h0b, apx, apq, apg2, apg1);
    hipLaunchKernelGGL(k_xx_mfma,   dim3(216),  dim3(256), 0, stream, xb, apx, xxb);
    hipLaunchKernelGGL(k_qkv_mfma,  dim3(576),  dim3(384), 0, stream, xxb, h0b, apq, qT, kT, vB);
    hipLaunchKernelGGL(k_attn_mfma, dim3(1344), dim3(256), 0, stream, qT, kT, vB, ab);
    hipLaunchKernelGGL(k_gates_mfma,dim3(576),  dim3(256), 0, stream, xxb, h0b, c0, ab,
                       apg2, apg1, bi, bf, bg, bo, out);
}